// Round 2
// baseline (3036.756 us; speedup 1.0000x reference)
//
#include <hip/hip_runtime.h>
#include <hip/hip_bf16.h>
#include <math.h>

#define B_ 4
#define H_ 128
#define W_ 128
#define DIM_ 128
#define HEADS_ 8
#define DH_ 64
#define G_ 64
#define INNER_ 512
#define N_ 16384

__device__ __forceinline__ void fma16(float (&acc)[4][4], const float4 a, const float4 b) {
  acc[0][0] = fmaf(a.x, b.x, acc[0][0]);
  acc[0][1] = fmaf(a.x, b.y, acc[0][1]);
  acc[0][2] = fmaf(a.x, b.z, acc[0][2]);
  acc[0][3] = fmaf(a.x, b.w, acc[0][3]);
  acc[1][0] = fmaf(a.y, b.x, acc[1][0]);
  acc[1][1] = fmaf(a.y, b.y, acc[1][1]);
  acc[1][2] = fmaf(a.y, b.z, acc[1][2]);
  acc[1][3] = fmaf(a.y, b.w, acc[1][3]);
  acc[2][0] = fmaf(a.z, b.x, acc[2][0]);
  acc[2][1] = fmaf(a.z, b.y, acc[2][1]);
  acc[2][2] = fmaf(a.z, b.z, acc[2][2]);
  acc[2][3] = fmaf(a.z, b.w, acc[2][3]);
  acc[3][0] = fmaf(a.w, b.x, acc[3][0]);
  acc[3][1] = fmaf(a.w, b.y, acc[3][1]);
  acc[3][2] = fmaf(a.w, b.z, acc[3][2]);
  acc[3][3] = fmaf(a.w, b.w, acc[3][3]);
}

// wt[t][c][o] = w[o][c][t], t = ky*3+kx
__global__ __launch_bounds__(256) void transpose_conv_w_kernel(const float* __restrict__ w,
                                                               float* __restrict__ wt) {
  int idx = blockIdx.x * 256 + threadIdx.x;
  if (idx >= 9 * DIM_ * INNER_) return;
  int o = idx % INNER_;
  int c = (idx / INNER_) % DIM_;
  int tp = idx / (INNER_ * DIM_);
  wt[idx] = w[((size_t)o * DIM_ + c) * 9 + tp];
}

// wot[i][o] = wo[o][i]
__global__ __launch_bounds__(256) void transpose_wo_kernel(const float* __restrict__ wo,
                                                           float* __restrict__ wot) {
  int idx = blockIdx.x * 256 + threadIdx.x;
  if (idx >= INNER_ * DIM_) return;
  int o = idx % DIM_;
  int i = idx / DIM_;
  wot[idx] = wo[(size_t)o * INNER_ + i];
}

// Implicit-GEMM 3x3 SAME conv for ONE batch. NHWC in [H,W,128] -> NHWC out [H,W,512].
// grid: x = H*(W/64) = 256, y = 512/64 = 8; block 256.
__global__ __launch_bounds__(256) void conv3x3_kernel(const float* __restrict__ x,
                                                      const float* __restrict__ wt,   // [9][128][512]
                                                      const float* __restrict__ bias, // [512]
                                                      float* __restrict__ out) {
  __shared__ __align__(16) float A[32][68];   // [c][px]
  __shared__ __align__(16) float Bs[32][64];  // [c][oc]
  const int t = threadIdx.x;
  const int xseg = blockIdx.x & 1;
  const int yrow = blockIdx.x >> 1;
  const int x0 = xseg * 64;
  const int oc0 = blockIdx.y * 64;
  const int tx = t & 15;   // oc group
  const int ty = t >> 4;   // pixel group

  float acc[4][4] = {};

  for (int tap = 0; tap < 9; ++tap) {
    const int ky = tap / 3, kx = tap % 3;
    const int sy = yrow + ky - 1;
    const bool rowok = (sy >= 0) && (sy < H_);
    const float* xrow = x + (size_t)(rowok ? sy : 0) * W_ * DIM_;
    for (int c0 = 0; c0 < DIM_; c0 += 32) {
      __syncthreads();
      // stage A[cc][px] = x[sy][x0+px+kx-1][c0+cc]
      {
        const int cg = t & 7;
        const int pxh = t >> 3;  // 0..31
#pragma unroll
        for (int r = 0; r < 2; ++r) {
          const int p = pxh + r * 32;
          const int sx = x0 + p + kx - 1;
          float4 v = make_float4(0.f, 0.f, 0.f, 0.f);
          if (rowok && sx >= 0 && sx < W_)
            v = *reinterpret_cast<const float4*>(xrow + (size_t)sx * DIM_ + c0 + cg * 4);
          A[cg * 4 + 0][p] = v.x;
          A[cg * 4 + 1][p] = v.y;
          A[cg * 4 + 2][p] = v.z;
          A[cg * 4 + 3][p] = v.w;
        }
      }
      // stage Bs[kk][oc] = wt[tap][c0+kk][oc0+oc]
      {
        const int og = t & 15;
        const int kkh = t >> 4;  // 0..15
        const float* wp = wt + ((size_t)tap * DIM_ + c0) * INNER_ + oc0;
#pragma unroll
        for (int r = 0; r < 2; ++r) {
          const int k2 = kkh + r * 16;
          *reinterpret_cast<float4*>(&Bs[k2][og * 4]) =
              *reinterpret_cast<const float4*>(wp + (size_t)k2 * INNER_ + og * 4);
        }
      }
      __syncthreads();
#pragma unroll
      for (int kk = 0; kk < 32; ++kk) {
        const float4 a4 = *reinterpret_cast<const float4*>(&A[kk][ty * 4]);
        const float4 b4 = *reinterpret_cast<const float4*>(&Bs[kk][tx * 4]);
        fma16(acc, a4, b4);
      }
    }
  }
  const float4 bi = *reinterpret_cast<const float4*>(bias + oc0 + tx * 4);
#pragma unroll
  for (int i = 0; i < 4; ++i) {
    float4 v;
    v.x = acc[i][0] + bi.x;
    v.y = acc[i][1] + bi.y;
    v.z = acc[i][2] + bi.z;
    v.w = acc[i][3] + bi.w;
    float* op = out + (((size_t)yrow * W_) + x0 + ty * 4 + i) * INNER_ + oc0 + tx * 4;
    *reinterpret_cast<float4*>(op) = v;
  }
}

// ONE batch. Per (head, 256-pixel chunk): logits -> softmax -> write w back in place
// over x_mid, accumulate slice-token partial + norm partial via atomics.
// grid = 8*64 = 512, block 256.
__global__ __launch_bounds__(256) void slice_kernel(float* __restrict__ xw,        // [N][512] x_mid -> w
                                                    const float* __restrict__ fxg, // [N][512] fx_mid
                                                    const float* __restrict__ Ws,  // [64][64]
                                                    const float* __restrict__ bs,  // [64]
                                                    const float* __restrict__ temperature, // [8]
                                                    float* __restrict__ tok,       // [8][64][64] zeroed
                                                    float* __restrict__ nrm) {     // [8][64] zeroed
  __shared__ __align__(16) float xmT[64][68];  // [c][n]; later reused as wl[n][g]
  __shared__ __align__(16) float WsT[64][68];  // [c][g]
  __shared__ __align__(16) float fxl[64][68];  // [n][c]
  __shared__ float bsl[64];
  float (*wl)[68] = xmT;

  const int t = threadIdx.x;
  const int sub = blockIdx.x & 63;
  const int h = blockIdx.x >> 6;
  const int nbase = sub * 256;
  const int tx = t & 15;
  const int ty = t >> 4;

  // stage WsT (once)
  {
    const int cg = t & 15;
    const int gr = t >> 4;
#pragma unroll
    for (int r = 0; r < 4; ++r) {
      const int gg = gr + r * 16;
      const float4 v = *reinterpret_cast<const float4*>(Ws + (size_t)gg * DH_ + cg * 4);
      WsT[cg * 4 + 0][gg] = v.x;
      WsT[cg * 4 + 1][gg] = v.y;
      WsT[cg * 4 + 2][gg] = v.z;
      WsT[cg * 4 + 3][gg] = v.w;
    }
    if (t < 64) bsl[t] = bs[t];
  }
  float tmp = temperature[h];
  tmp = fminf(fmaxf(tmp, 0.1f), 5.0f);
  const float invt = 1.0f / tmp;

  float acc2[4][4] = {};  // token partial [g][c]
  float snrm = 0.0f;      // per-thread (t<64) norm partial

  for (int s = 0; s < 4; ++s) {
    const int n0 = nbase + s * 64;
    __syncthreads();
    // stage xmT[c][n], fxl[n][c]
    {
      const int cg = t & 15;
      const int nr = t >> 4;
#pragma unroll
      for (int r = 0; r < 4; ++r) {
        const int nn = nr + r * 16;
        const size_t rowoff = ((size_t)(n0 + nn)) * INNER_ + h * DH_ + cg * 4;
        const float4 v = *reinterpret_cast<const float4*>(xw + rowoff);
        xmT[cg * 4 + 0][nn] = v.x;
        xmT[cg * 4 + 1][nn] = v.y;
        xmT[cg * 4 + 2][nn] = v.z;
        xmT[cg * 4 + 3][nn] = v.w;
        *reinterpret_cast<float4*>(&fxl[nn][cg * 4]) =
            *reinterpret_cast<const float4*>(fxg + rowoff);
      }
    }
    __syncthreads();
    // logits GEMM: l[n][g] = sum_c xmT[c][n]*WsT[c][g]
    float lacc[4][4] = {};
#pragma unroll
    for (int kk = 0; kk < 64; ++kk) {
      const float4 a4 = *reinterpret_cast<const float4*>(&xmT[kk][ty * 4]);
      const float4 b4 = *reinterpret_cast<const float4*>(&WsT[kk][tx * 4]);
      fma16(lacc, a4, b4);
    }
    __syncthreads();  // done reading xmT; safe to overwrite as wl
#pragma unroll
    for (int i = 0; i < 4; ++i)
#pragma unroll
      for (int j = 0; j < 4; ++j)
        wl[ty * 4 + i][tx * 4 + j] = (lacc[i][j] + bsl[tx * 4 + j]) * invt;
    __syncthreads();
    // softmax over g per row n
    if (t < 64) {
      float m = -3.4e38f;
#pragma unroll
      for (int g = 0; g < 64; ++g) m = fmaxf(m, wl[t][g]);
      float ssum = 0.0f;
#pragma unroll
      for (int g = 0; g < 64; ++g) {
        const float e = __expf(wl[t][g] - m);
        wl[t][g] = e;
        ssum += e;
      }
      const float inv = 1.0f / ssum;
#pragma unroll
      for (int g = 0; g < 64; ++g) wl[t][g] *= inv;
    }
    __syncthreads();
    // write w back to global (in place over x_mid region of this (h,chunk))
    {
      const int gg = t & 15;
      const int nr = t >> 4;
#pragma unroll
      for (int r = 0; r < 4; ++r) {
        const int nn = nr + r * 16;
        *reinterpret_cast<float4*>(xw + ((size_t)(n0 + nn)) * INNER_ + h * DH_ + gg * 4) =
            *reinterpret_cast<float4*>(&wl[nn][gg * 4]);
      }
    }
    // norm partial
    if (t < 64) {
#pragma unroll
      for (int n = 0; n < 64; ++n) snrm += wl[n][t];
    }
    // token GEMM partial: acc2[g][c] += sum_n wl[n][g]*fxl[n][c]
#pragma unroll
    for (int kk = 0; kk < 64; ++kk) {
      const float4 a4 = *reinterpret_cast<const float4*>(&wl[kk][ty * 4]);
      const float4 b4 = *reinterpret_cast<const float4*>(&fxl[kk][tx * 4]);
      fma16(acc2, a4, b4);
    }
    __syncthreads();  // before next sub overwrites LDS
  }
  // flush partials
  float* tokp = tok + (size_t)h * G_ * DH_;
#pragma unroll
  for (int i = 0; i < 4; ++i)
#pragma unroll
    for (int j = 0; j < 4; ++j)
      atomicAdd(tokp + (size_t)(ty * 4 + i) * DH_ + tx * 4 + j, acc2[i][j]);
  if (t < 64) atomicAdd(nrm + (size_t)h * G_ + t, snrm);
}

// ONE batch. q/k/v = slice_token x W^T.  grid 8 (head), block 256. qkv layout [m][h][g][d]
__global__ __launch_bounds__(256) void qkv_kernel(const float* __restrict__ tok,
                                                  const float* __restrict__ nrm,
                                                  const float* __restrict__ Wq,
                                                  const float* __restrict__ Wk,
                                                  const float* __restrict__ Wv,
                                                  float* __restrict__ qkv) {
  __shared__ float st[64][65];
  __shared__ float wb[64][65];
  const int t = threadIdx.x;
  const int h = blockIdx.x;
  for (int e = t; e < 4096; e += 256) {
    const int g = e >> 6;
    st[g][e & 63] = tok[(size_t)h * 4096 + e] / (nrm[(size_t)h * 64 + g] + 1e-5f);
  }
  const float* Wp[3] = {Wq, Wk, Wv};
  for (int m = 0; m < 3; ++m) {
    __syncthreads();
    for (int e = t; e < 4096; e += 256) wb[e >> 6][e & 63] = Wp[m][e];
    __syncthreads();
    for (int e = t; e < 4096; e += 256) {
      const int g = e >> 6, d = e & 63;
      float s = 0.0f;
#pragma unroll
      for (int c = 0; c < 64; ++c) s = fmaf(st[g][c], wb[d][c], s);
      qkv[((size_t)m * HEADS_ + h) * 4096 + e] = s;
    }
  }
}

// ONE batch. dots -> softmax -> out_slice. grid 8, block 256.
__global__ __launch_bounds__(256) void attn_kernel(const float* __restrict__ qkv,
                                                   float* __restrict__ osl) {
  __shared__ float X[64][65];
  __shared__ float Y[64][65];
  __shared__ float Z[64][65];
  const int t = threadIdx.x;
  const int h = blockIdx.x;
  for (int e = t; e < 4096; e += 256) {
    X[e >> 6][e & 63] = qkv[(size_t)h * 4096 + e];                        // q
    Y[e >> 6][e & 63] = qkv[((size_t)HEADS_ + h) * 4096 + e];             // k
  }
  __syncthreads();
  for (int e = t; e < 4096; e += 256) {
    const int g = e >> 6, kx = e & 63;
    float s = 0.0f;
#pragma unroll
    for (int d = 0; d < 64; ++d) s = fmaf(X[g][d], Y[kx][d], s);
    Z[g][kx] = s * 0.125f;
  }
  __syncthreads();
  // reload X = v; softmax rows of Z
  for (int e = t; e < 4096; e += 256)
    X[e >> 6][e & 63] = qkv[((size_t)2 * HEADS_ + h) * 4096 + e];         // v
  if (t < 64) {
    float m = -3.4e38f;
#pragma unroll
    for (int k = 0; k < 64; ++k) m = fmaxf(m, Z[t][k]);
    float ssum = 0.0f;
#pragma unroll
    for (int k = 0; k < 64; ++k) {
      const float e2 = __expf(Z[t][k] - m);
      Z[t][k] = e2;
      ssum += e2;
    }
    const float inv = 1.0f / ssum;
#pragma unroll
    for (int k = 0; k < 64; ++k) Z[t][k] *= inv;
  }
  __syncthreads();
  for (int e = t; e < 4096; e += 256) {
    const int g = e >> 6, d = e & 63;
    float s = 0.0f;
#pragma unroll
    for (int k = 0; k < 64; ++k) s = fmaf(Z[g][k], X[k][d], s);
    osl[(size_t)h * 4096 + e] = s;
  }
}

// ONE batch. out_x[n][h*64+d] = sum_g w[n][g]*os[g][d].  grid 8*256 = 2048, block 256.
__global__ __launch_bounds__(256) void scatter_kernel(const float* __restrict__ xw,  // w in [n][h*64+g]
                                                      const float* __restrict__ osl, // [h][g][d]
                                                      float* __restrict__ fxo) {     // out_x [n][512]
  __shared__ __align__(16) float wT[64][68];  // [g][n]
  __shared__ __align__(16) float os[64][68];  // [g][d]
  const int t = threadIdx.x;
  const int chunk = blockIdx.x & 255;
  const int h = blockIdx.x >> 8;
  const int n0 = chunk * 64;
  {
    const int gg = t & 15;
    const int nr = t >> 4;
#pragma unroll
    for (int r = 0; r < 4; ++r) {
      const int nn = nr + r * 16;
      const float4 v = *reinterpret_cast<const float4*>(
          xw + ((size_t)(n0 + nn)) * INNER_ + h * DH_ + gg * 4);
      wT[gg * 4 + 0][nn] = v.x;
      wT[gg * 4 + 1][nn] = v.y;
      wT[gg * 4 + 2][nn] = v.z;
      wT[gg * 4 + 3][nn] = v.w;
    }
    const int dg = t & 15;
    const int gr = t >> 4;
#pragma unroll
    for (int r = 0; r < 4; ++r) {
      const int g2 = gr + r * 16;
      *reinterpret_cast<float4*>(&os[g2][dg * 4]) =
          *reinterpret_cast<const float4*>(osl + ((size_t)h * G_ + g2) * DH_ + dg * 4);
    }
  }
  __syncthreads();
  const int tx = t & 15;  // d group
  const int ty = t >> 4;  // n group
  float acc[4][4] = {};
#pragma unroll
  for (int kk = 0; kk < 64; ++kk) {
    const float4 a4 = *reinterpret_cast<const float4*>(&wT[kk][ty * 4]);
    const float4 b4 = *reinterpret_cast<const float4*>(&os[kk][tx * 4]);
    fma16(acc, a4, b4);
  }
#pragma unroll
  for (int i = 0; i < 4; ++i) {
    float4 v;
    v.x = acc[i][0];
    v.y = acc[i][1];
    v.z = acc[i][2];
    v.w = acc[i][3];
    *reinterpret_cast<float4*>(fxo + ((size_t)(n0 + ty * 4 + i)) * INNER_ + h * DH_ + tx * 4) = v;
  }
}

// ONE batch. out[p][o] = sum_i out_x[p][i]*WoT[i][o] + bo[o].  grid 16384/32 = 512, block 256.
__global__ __launch_bounds__(256) void out_gemm_kernel(const float* __restrict__ fxo,  // [N][512]
                                                       const float* __restrict__ wot,  // [512][128]
                                                       const float* __restrict__ bo,   // [128]
                                                       float* __restrict__ out) {      // [N][128]
  __shared__ __align__(16) float aT[32][36];   // [kk][px]
  __shared__ __align__(16) float bT[32][128];  // [kk][o]
  const int t = threadIdx.x;
  const int p0 = blockIdx.x * 32;
  const int tx = t & 31;  // o group (o = tx*4)
  const int ty = t >> 5;  // px group (px = ty*4), 8 groups
  float acc[4][4] = {};
  for (int k0 = 0; k0 < INNER_; k0 += 32) {
    __syncthreads();
    {
      const int kg = t & 7;
      const int px = t >> 3;  // 0..31
      const float4 v = *reinterpret_cast<const float4*>(fxo + ((size_t)(p0 + px)) * INNER_ + k0 + kg * 4);
      aT[kg * 4 + 0][px] = v.x;
      aT[kg * 4 + 1][px] = v.y;
      aT[kg * 4 + 2][px] = v.z;
      aT[kg * 4 + 3][px] = v.w;
    }
    {
      const int og = t & 31;
      const int kkh = t >> 5;  // 0..7
#pragma unroll
      for (int r = 0; r < 4; ++r) {
        const int k2 = kkh + r * 8;
        *reinterpret_cast<float4*>(&bT[k2][og * 4]) =
            *reinterpret_cast<const float4*>(wot + (size_t)(k0 + k2) * DIM_ + og * 4);
      }
    }
    __syncthreads();
#pragma unroll
    for (int kk = 0; kk < 32; ++kk) {
      const float4 a4 = *reinterpret_cast<const float4*>(&aT[kk][ty * 4]);
      const float4 b4 = *reinterpret_cast<const float4*>(&bT[kk][tx * 4]);
      fma16(acc, a4, b4);
    }
  }
  const float4 bi = *reinterpret_cast<const float4*>(bo + tx * 4);
#pragma unroll
  for (int i = 0; i < 4; ++i) {
    float4 v;
    v.x = acc[i][0] + bi.x;
    v.y = acc[i][1] + bi.y;
    v.z = acc[i][2] + bi.z;
    v.w = acc[i][3] + bi.w;
    *reinterpret_cast<float4*>(out + (size_t)(p0 + ty * 4 + i) * DIM_ + tx * 4) = v;
  }
}

extern "C" void kernel_launch(void* const* d_in, const int* in_sizes, int n_in,
                              void* d_out, int out_size, void* d_ws, size_t ws_size,
                              hipStream_t stream) {
  const float* x    = (const float*)d_in[0];
  const float* temp = (const float*)d_in[1];
  const float* Wx   = (const float*)d_in[2];
  const float* bx   = (const float*)d_in[3];
  const float* Wfx  = (const float*)d_in[4];
  const float* bfx  = (const float*)d_in[5];
  const float* Ws   = (const float*)d_in[6];
  const float* bs   = (const float*)d_in[7];
  const float* Wq   = (const float*)d_in[8];
  const float* Wk   = (const float*)d_in[9];
  const float* Wv   = (const float*)d_in[10];
  const float* Wo   = (const float*)d_in[11];
  const float* bo   = (const float*)d_in[12];
  float* out = (float*)d_out;

  // Per-batch workspace layout (~73 MB total, fits comfortably in d_ws):
  float* ws = (float*)d_ws;
  float* WtX = ws;                       // 589824
  float* WtF = WtX + 589824;             // 589824
  float* WoT = WtF + 589824;             // 65536
  float* XW  = WoT + 65536;              // 8388608   (x_mid -> w, one batch)
  float* FXO = XW + 8388608;             // 8388608   (fx_mid -> out_x, one batch)
  float* TOK = FXO + 8388608;            // 131072    ([B][8][64][64])
  float* NRM = TOK + 131072;             // 2048      ([B][8][64])
  float* OSL = NRM + 2048;               // 32768     (one batch [8][64][64])
  float* QKV = OSL + 32768;              // 98304     (one batch [3][8][64][64])

  hipMemsetAsync(TOK, 0, (131072 + 2048) * sizeof(float), stream);
  transpose_conv_w_kernel<<<2304, 256, 0, stream>>>(Wx, WtX);
  transpose_conv_w_kernel<<<2304, 256, 0, stream>>>(Wfx, WtF);
  transpose_wo_kernel<<<256, 256, 0, stream>>>(Wo, WoT);

  for (int b = 0; b < B_; ++b) {
    const float* xb = x + (size_t)b * N_ * DIM_;
    float* outb = out + (size_t)b * N_ * DIM_;
    float* tokb = TOK + (size_t)b * HEADS_ * G_ * DH_;
    float* nrmb = NRM + (size_t)b * HEADS_ * G_;

    conv3x3_kernel<<<dim3(256, 8), 256, 0, stream>>>(xb, WtX, bx, XW);
    conv3x3_kernel<<<dim3(256, 8), 256, 0, stream>>>(xb, WtF, bfx, FXO);
    slice_kernel<<<512, 256, 0, stream>>>(XW, FXO, Ws, bs, temp, tokb, nrmb);
    qkv_kernel<<<8, 256, 0, stream>>>(tokb, nrmb, Wq, Wk, Wv, QKV);
    attn_kernel<<<8, 256, 0, stream>>>(QKV, OSL);
    scatter_kernel<<<2048, 256, 0, stream>>>(XW, OSL, FXO);
    out_gemm_kernel<<<512, 256, 0, stream>>>(FXO, WoT, bo, outb);
  }
}

// Round 3
// 1512.821 us; speedup vs baseline: 2.0073x; 2.0073x over previous
//
#include <hip/hip_runtime.h>
#include <hip/hip_bf16.h>
#include <math.h>

#define B_ 4
#define H_ 128
#define W_ 128
#define DIM_ 128
#define HEADS_ 8
#define DH_ 64
#define G_ 64
#define INNER_ 512
#define N_ 16384
#define PW_ 130  // padded H/W

typedef __attribute__((ext_vector_type(8))) short sh8;
typedef __attribute__((ext_vector_type(4))) float vf4;

__device__ __forceinline__ void gload16(const void* g, void* l) {
  __builtin_amdgcn_global_load_lds((const __attribute__((address_space(1))) void*)g,
                                   (__attribute__((address_space(3))) void*)l, 16, 0, 0);
}

__device__ __forceinline__ void split_bf16(float v, ushort& h, ushort& l) {
  __hip_bfloat16 hb = __float2bfloat16(v);
  float hf = __bfloat162float(hb);
  __hip_bfloat16 lb = __float2bfloat16(v - hf);
  h = *reinterpret_cast<ushort*>(&hb);
  l = *reinterpret_cast<ushort*>(&lb);
}

// ---- prep: pad one batch of x into hi/lo bf16 [130][130][128], zero border ----
__global__ __launch_bounds__(256) void pad_split_kernel(const float* __restrict__ x,
                                                        ushort* __restrict__ xph,
                                                        ushort* __restrict__ xpl) {
  int idx = blockIdx.x * 256 + threadIdx.x;
  if (idx >= PW_ * PW_ * DIM_) return;
  const int c = idx & 127;
  const int px = (idx >> 7) % PW_;
  const int py = (idx >> 7) / PW_;
  float v = 0.0f;
  if (py >= 1 && py <= H_ && px >= 1 && px <= W_)
    v = x[(((size_t)(py - 1)) * W_ + (px - 1)) * DIM_ + c];
  split_bf16(v, xph[idx], xpl[idx]);
}

// ---- prep: combined conv weights -> [9][1024][128] hi/lo bf16 (oc-major, c contiguous) ----
__global__ __launch_bounds__(256) void wprep_kernel(const float* __restrict__ Wx,
                                                    const float* __restrict__ Wfx,
                                                    ushort* __restrict__ wth,
                                                    ushort* __restrict__ wtl) {
  int idx = blockIdx.x * 256 + threadIdx.x;
  if (idx >= 9 * 1024 * DIM_) return;
  const int c = idx & 127;
  const int oc = (idx >> 7) & 1023;
  const int tap = idx >> 17;
  float v;
  if (oc < INNER_) v = Wx[((size_t)oc * DIM_ + c) * 9 + tap];
  else             v = Wfx[((size_t)(oc - INNER_) * DIM_ + c) * 9 + tap];
  split_bf16(v, wth[idx], wtl[idx]);
}

// ---- fused bf16x3 MFMA conv: one batch, BOTH convs (N=1024 combined) ----
// grid (128 rows, 8 oc-tiles), block 256 (4 waves).
// Per block: 128 pixels (one image row) x 128 ocs, K = 9 taps * 128 ch.
__global__ __launch_bounds__(256) void conv_mfma_kernel(
    const ushort* __restrict__ xph, const ushort* __restrict__ xpl,
    const ushort* __restrict__ wth, const ushort* __restrict__ wtl,
    const float* __restrict__ bx, const float* __restrict__ bfx,
    float* __restrict__ xw, float* __restrict__ fxo) {
  // regions (shorts): Ah 0, Al 4096, Bh 8192, Bl 12288; each [4 kgroup][128][8ch]
  __shared__ __align__(16) ushort lds[16384];  // 32 KB
  const int t = threadIdx.x;
  const int lane = t & 63;
  const int wid = t >> 6;
  const int wm = wid & 1, wn = wid >> 1;
  const int y = blockIdx.x;
  const int n0 = blockIdx.y * 128;  // combined oc base 0..896

  const int col = lane & 15;
  const int quad = lane >> 4;

  // staging: per-thread global-element offsets and LDS dests.
  // round i covers bytes i*4096 + t*16 of a region: kgroup = i*2 + (t>>7), pix = t&127.
  const int pixs = t & 127;
  const int kg = t >> 7;  // 0/1
  const int goff0 = pixs * DIM_ + kg * 8;  // elements
  const int goff1 = goff0 + 16;            // kgroup + 2
  ushort* l0 = lds + t * 8;          // byte t*16
  ushort* l1 = lds + 2048 + t * 8;   // byte 4096 + t*16

  // fragment read offsets (shorts): quad*2048B + (row)*16B
  const int a_rd = quad * 1024 + (wm * 64 + col) * 8;
  const int b_rd = quad * 1024 + (wn * 64 + col) * 8;

  vf4 acc[4][4];
#pragma unroll
  for (int i = 0; i < 4; ++i)
#pragma unroll
    for (int j = 0; j < 4; ++j) acc[i][j] = vf4{0.f, 0.f, 0.f, 0.f};

  for (int tap = 0; tap < 9; ++tap) {
    const int ky = tap / 3, kx = tap % 3;
    const ushort* aH = xph + ((size_t)(y + ky) * PW_ + kx) * DIM_;
    const ushort* aL = xpl + ((size_t)(y + ky) * PW_ + kx) * DIM_;
    const ushort* bH = wth + ((size_t)tap * 1024 + n0) * DIM_;
    const ushort* bL = wtl + ((size_t)tap * 1024 + n0) * DIM_;
    for (int c0 = 0; c0 < DIM_; c0 += 32) {
      __syncthreads();  // previous chunk's ds_reads done
      gload16(aH + c0 + goff0, l0);
      gload16(aH + c0 + goff1, l1);
      gload16(aL + c0 + goff0, l0 + 4096);
      gload16(aL + c0 + goff1, l1 + 4096);
      gload16(bH + c0 + goff0, l0 + 8192);
      gload16(bH + c0 + goff1, l1 + 8192);
      gload16(bL + c0 + goff0, l0 + 12288);
      gload16(bL + c0 + goff1, l1 + 12288);
      __syncthreads();  // staging complete (compiler drains vmcnt before barrier)
      sh8 ah[4], al[4], bh[4], bl[4];
#pragma unroll
      for (int i = 0; i < 4; ++i) {
        ah[i] = *reinterpret_cast<const sh8*>(lds + a_rd + i * 128);
        al[i] = *reinterpret_cast<const sh8*>(lds + 4096 + a_rd + i * 128);
        bh[i] = *reinterpret_cast<const sh8*>(lds + 8192 + b_rd + i * 128);
        bl[i] = *reinterpret_cast<const sh8*>(lds + 12288 + b_rd + i * 128);
      }
#pragma unroll
      for (int i = 0; i < 4; ++i)
#pragma unroll
        for (int j = 0; j < 4; ++j) {
          acc[i][j] = __builtin_amdgcn_mfma_f32_16x16x32_bf16(ah[i], bh[j], acc[i][j], 0, 0, 0);
          acc[i][j] = __builtin_amdgcn_mfma_f32_16x16x32_bf16(ah[i], bl[j], acc[i][j], 0, 0, 0);
          acc[i][j] = __builtin_amdgcn_mfma_f32_16x16x32_bf16(al[i], bh[j], acc[i][j], 0, 0, 0);
        }
    }
  }
  // epilogue: C/D layout col=lane&15 (oc), row=quad*4+reg (pixel)
  const bool first = (blockIdx.y < 4);
  float* outp = first ? xw : fxo;
  const float* bb = first ? bx : bfx;
  const int ocbase = (blockIdx.y & 3) * 128 + wn * 64 + col;
#pragma unroll
  for (int j = 0; j < 4; ++j) {
    const int oc = ocbase + j * 16;
    const float bv = bb[oc];
#pragma unroll
    for (int i = 0; i < 4; ++i) {
#pragma unroll
      for (int r = 0; r < 4; ++r) {
        const int px = wm * 64 + i * 16 + quad * 4 + r;
        outp[((size_t)(y * W_ + px)) * INNER_ + oc] = acc[i][j][r] + bv;
      }
    }
  }
}

__device__ __forceinline__ void fma16(float (&acc)[4][4], const float4 a, const float4 b) {
  acc[0][0] = fmaf(a.x, b.x, acc[0][0]);
  acc[0][1] = fmaf(a.x, b.y, acc[0][1]);
  acc[0][2] = fmaf(a.x, b.z, acc[0][2]);
  acc[0][3] = fmaf(a.x, b.w, acc[0][3]);
  acc[1][0] = fmaf(a.y, b.x, acc[1][0]);
  acc[1][1] = fmaf(a.y, b.y, acc[1][1]);
  acc[1][2] = fmaf(a.y, b.z, acc[1][2]);
  acc[1][3] = fmaf(a.y, b.w, acc[1][3]);
  acc[2][0] = fmaf(a.z, b.x, acc[2][0]);
  acc[2][1] = fmaf(a.z, b.y, acc[2][1]);
  acc[2][2] = fmaf(a.z, b.z, acc[2][2]);
  acc[2][3] = fmaf(a.z, b.w, acc[2][3]);
  acc[3][0] = fmaf(a.w, b.x, acc[3][0]);
  acc[3][1] = fmaf(a.w, b.y, acc[3][1]);
  acc[3][2] = fmaf(a.w, b.z, acc[3][2]);
  acc[3][3] = fmaf(a.w, b.w, acc[3][3]);
}

// wot[i][o] = wo[o][i]
__global__ __launch_bounds__(256) void transpose_wo_kernel(const float* __restrict__ wo,
                                                           float* __restrict__ wot) {
  int idx = blockIdx.x * 256 + threadIdx.x;
  if (idx >= INNER_ * DIM_) return;
  int o = idx % DIM_;
  int i = idx / DIM_;
  wot[idx] = wo[(size_t)o * INNER_ + i];
}

// ONE batch. Per (head, 256-pixel chunk): logits -> softmax -> w in place over x_mid,
// token + norm partials via atomics. grid 512, block 256.
__global__ __launch_bounds__(256) void slice_kernel(float* __restrict__ xw,
                                                    const float* __restrict__ fxg,
                                                    const float* __restrict__ Ws,
                                                    const float* __restrict__ bs,
                                                    const float* __restrict__ temperature,
                                                    float* __restrict__ tok,
                                                    float* __restrict__ nrm) {
  __shared__ __align__(16) float xmT[64][68];
  __shared__ __align__(16) float WsT[64][68];
  __shared__ __align__(16) float fxl[64][68];
  __shared__ float bsl[64];
  float (*wl)[68] = xmT;

  const int t = threadIdx.x;
  const int sub = blockIdx.x & 63;
  const int h = blockIdx.x >> 6;
  const int nbase = sub * 256;
  const int tx = t & 15;
  const int ty = t >> 4;

  {
    const int cg = t & 15;
    const int gr = t >> 4;
#pragma unroll
    for (int r = 0; r < 4; ++r) {
      const int gg = gr + r * 16;
      const float4 v = *reinterpret_cast<const float4*>(Ws + (size_t)gg * DH_ + cg * 4);
      WsT[cg * 4 + 0][gg] = v.x;
      WsT[cg * 4 + 1][gg] = v.y;
      WsT[cg * 4 + 2][gg] = v.z;
      WsT[cg * 4 + 3][gg] = v.w;
    }
    if (t < 64) bsl[t] = bs[t];
  }
  float tmp = temperature[h];
  tmp = fminf(fmaxf(tmp, 0.1f), 5.0f);
  const float invt = 1.0f / tmp;

  float acc2[4][4] = {};
  float snrm = 0.0f;

  for (int s = 0; s < 4; ++s) {
    const int n0 = nbase + s * 64;
    __syncthreads();
    {
      const int cg = t & 15;
      const int nr = t >> 4;
#pragma unroll
      for (int r = 0; r < 4; ++r) {
        const int nn = nr + r * 16;
        const size_t rowoff = ((size_t)(n0 + nn)) * INNER_ + h * DH_ + cg * 4;
        const float4 v = *reinterpret_cast<const float4*>(xw + rowoff);
        xmT[cg * 4 + 0][nn] = v.x;
        xmT[cg * 4 + 1][nn] = v.y;
        xmT[cg * 4 + 2][nn] = v.z;
        xmT[cg * 4 + 3][nn] = v.w;
        *reinterpret_cast<float4*>(&fxl[nn][cg * 4]) =
            *reinterpret_cast<const float4*>(fxg + rowoff);
      }
    }
    __syncthreads();
    float lacc[4][4] = {};
#pragma unroll
    for (int kk = 0; kk < 64; ++kk) {
      const float4 a4 = *reinterpret_cast<const float4*>(&xmT[kk][ty * 4]);
      const float4 b4 = *reinterpret_cast<const float4*>(&WsT[kk][tx * 4]);
      fma16(lacc, a4, b4);
    }
    __syncthreads();
#pragma unroll
    for (int i = 0; i < 4; ++i)
#pragma unroll
      for (int j = 0; j < 4; ++j)
        wl[ty * 4 + i][tx * 4 + j] = (lacc[i][j] + bsl[tx * 4 + j]) * invt;
    __syncthreads();
    if (t < 64) {
      float m = -3.4e38f;
#pragma unroll
      for (int g = 0; g < 64; ++g) m = fmaxf(m, wl[t][g]);
      float ssum = 0.0f;
#pragma unroll
      for (int g = 0; g < 64; ++g) {
        const float e = __expf(wl[t][g] - m);
        wl[t][g] = e;
        ssum += e;
      }
      const float inv = 1.0f / ssum;
#pragma unroll
      for (int g = 0; g < 64; ++g) wl[t][g] *= inv;
    }
    __syncthreads();
    {
      const int gg = t & 15;
      const int nr = t >> 4;
#pragma unroll
      for (int r = 0; r < 4; ++r) {
        const int nn = nr + r * 16;
        *reinterpret_cast<float4*>(xw + ((size_t)(n0 + nn)) * INNER_ + h * DH_ + gg * 4) =
            *reinterpret_cast<float4*>(&wl[nn][gg * 4]);
      }
    }
    if (t < 64) {
#pragma unroll
      for (int n = 0; n < 64; ++n) snrm += wl[n][t];
    }
#pragma unroll
    for (int kk = 0; kk < 64; ++kk) {
      const float4 a4 = *reinterpret_cast<const float4*>(&wl[kk][ty * 4]);
      const float4 b4 = *reinterpret_cast<const float4*>(&fxl[kk][tx * 4]);
      fma16(acc2, a4, b4);
    }
    __syncthreads();
  }
  float* tokp = tok + (size_t)h * G_ * DH_;
#pragma unroll
  for (int i = 0; i < 4; ++i)
#pragma unroll
    for (int j = 0; j < 4; ++j)
      atomicAdd(tokp + (size_t)(ty * 4 + i) * DH_ + tx * 4 + j, acc2[i][j]);
  if (t < 64) atomicAdd(nrm + (size_t)h * G_ + t, snrm);
}

// ONE batch. grid 8, block 256. qkv layout [m][h][g][d]
__global__ __launch_bounds__(256) void qkv_kernel(const float* __restrict__ tok,
                                                  const float* __restrict__ nrm,
                                                  const float* __restrict__ Wq,
                                                  const float* __restrict__ Wk,
                                                  const float* __restrict__ Wv,
                                                  float* __restrict__ qkv) {
  __shared__ float st[64][65];
  __shared__ float wb[64][65];
  const int t = threadIdx.x;
  const int h = blockIdx.x;
  for (int e = t; e < 4096; e += 256) {
    const int g = e >> 6;
    st[g][e & 63] = tok[(size_t)h * 4096 + e] / (nrm[(size_t)h * 64 + g] + 1e-5f);
  }
  const float* Wp[3] = {Wq, Wk, Wv};
  for (int m = 0; m < 3; ++m) {
    __syncthreads();
    for (int e = t; e < 4096; e += 256) wb[e >> 6][e & 63] = Wp[m][e];
    __syncthreads();
    for (int e = t; e < 4096; e += 256) {
      const int g = e >> 6, d = e & 63;
      float s = 0.0f;
#pragma unroll
      for (int c = 0; c < 64; ++c) s = fmaf(st[g][c], wb[d][c], s);
      qkv[((size_t)m * HEADS_ + h) * 4096 + e] = s;
    }
  }
}

// ONE batch. grid 8, block 256.
__global__ __launch_bounds__(256) void attn_kernel(const float* __restrict__ qkv,
                                                   float* __restrict__ osl) {
  __shared__ float X[64][65];
  __shared__ float Y[64][65];
  __shared__ float Z[64][65];
  const int t = threadIdx.x;
  const int h = blockIdx.x;
  for (int e = t; e < 4096; e += 256) {
    X[e >> 6][e & 63] = qkv[(size_t)h * 4096 + e];
    Y[e >> 6][e & 63] = qkv[((size_t)HEADS_ + h) * 4096 + e];
  }
  __syncthreads();
  for (int e = t; e < 4096; e += 256) {
    const int g = e >> 6, kx = e & 63;
    float s = 0.0f;
#pragma unroll
    for (int d = 0; d < 64; ++d) s = fmaf(X[g][d], Y[kx][d], s);
    Z[g][kx] = s * 0.125f;
  }
  __syncthreads();
  for (int e = t; e < 4096; e += 256)
    X[e >> 6][e & 63] = qkv[((size_t)2 * HEADS_ + h) * 4096 + e];
  if (t < 64) {
    float m = -3.4e38f;
#pragma unroll
    for (int k = 0; k < 64; ++k) m = fmaxf(m, Z[t][k]);
    float ssum = 0.0f;
#pragma unroll
    for (int k = 0; k < 64; ++k) {
      const float e2 = __expf(Z[t][k] - m);
      Z[t][k] = e2;
      ssum += e2;
    }
    const float inv = 1.0f / ssum;
#pragma unroll
    for (int k = 0; k < 64; ++k) Z[t][k] *= inv;
  }
  __syncthreads();
  for (int e = t; e < 4096; e += 256) {
    const int g = e >> 6, d = e & 63;
    float s = 0.0f;
#pragma unroll
    for (int k = 0; k < 64; ++k) s = fmaf(Z[g][k], X[k][d], s);
    osl[(size_t)h * 4096 + e] = s;
  }
}

// ONE batch. grid 2048, block 256.
__global__ __launch_bounds__(256) void scatter_kernel(const float* __restrict__ xw,
                                                      const float* __restrict__ osl,
                                                      float* __restrict__ fxo) {
  __shared__ __align__(16) float wT[64][68];
  __shared__ __align__(16) float os[64][68];
  const int t = threadIdx.x;
  const int chunk = blockIdx.x & 255;
  const int h = blockIdx.x >> 8;
  const int n0 = chunk * 64;
  {
    const int gg = t & 15;
    const int nr = t >> 4;
#pragma unroll
    for (int r = 0; r < 4; ++r) {
      const int nn = nr + r * 16;
      const float4 v = *reinterpret_cast<const float4*>(
          xw + ((size_t)(n0 + nn)) * INNER_ + h * DH_ + gg * 4);
      wT[gg * 4 + 0][nn] = v.x;
      wT[gg * 4 + 1][nn] = v.y;
      wT[gg * 4 + 2][nn] = v.z;
      wT[gg * 4 + 3][nn] = v.w;
    }
    const int dg = t & 15;
    const int gr = t >> 4;
#pragma unroll
    for (int r = 0; r < 4; ++r) {
      const int g2 = gr + r * 16;
      *reinterpret_cast<float4*>(&os[g2][dg * 4]) =
          *reinterpret_cast<const float4*>(osl + ((size_t)h * G_ + g2) * DH_ + dg * 4);
    }
  }
  __syncthreads();
  const int tx = t & 15;
  const int ty = t >> 4;
  float acc[4][4] = {};
#pragma unroll
  for (int kk = 0; kk < 64; ++kk) {
    const float4 a4 = *reinterpret_cast<const float4*>(&wT[kk][ty * 4]);
    const float4 b4 = *reinterpret_cast<const float4*>(&os[kk][tx * 4]);
    fma16(acc, a4, b4);
  }
#pragma unroll
  for (int i = 0; i < 4; ++i) {
    float4 v;
    v.x = acc[i][0];
    v.y = acc[i][1];
    v.z = acc[i][2];
    v.w = acc[i][3];
    *reinterpret_cast<float4*>(fxo + ((size_t)(n0 + ty * 4 + i)) * INNER_ + h * DH_ + tx * 4) = v;
  }
}

// ONE batch. grid 512, block 256.
__global__ __launch_bounds__(256) void out_gemm_kernel(const float* __restrict__ fxo,
                                                       const float* __restrict__ wot,
                                                       const float* __restrict__ bo,
                                                       float* __restrict__ out) {
  __shared__ __align__(16) float aT[32][36];
  __shared__ __align__(16) float bT[32][128];
  const int t = threadIdx.x;
  const int p0 = blockIdx.x * 32;
  const int tx = t & 31;
  const int ty = t >> 5;
  float acc[4][4] = {};
  for (int k0 = 0; k0 < INNER_; k0 += 32) {
    __syncthreads();
    {
      const int kg = t & 7;
      const int px = t >> 3;
      const float4 v = *reinterpret_cast<const float4*>(fxo + ((size_t)(p0 + px)) * INNER_ + k0 + kg * 4);
      aT[kg * 4 + 0][px] = v.x;
      aT[kg * 4 + 1][px] = v.y;
      aT[kg * 4 + 2][px] = v.z;
      aT[kg * 4 + 3][px] = v.w;
    }
    {
      const int og = t & 31;
      const int kkh = t >> 5;
#pragma unroll
      for (int r = 0; r < 4; ++r) {
        const int k2 = kkh + r * 8;
        *reinterpret_cast<float4*>(&bT[k2][og * 4]) =
            *reinterpret_cast<const float4*>(wot + (size_t)(k0 + k2) * DIM_ + og * 4);
      }
    }
    __syncthreads();
#pragma unroll
    for (int kk = 0; kk < 32; ++kk) {
      const float4 a4 = *reinterpret_cast<const float4*>(&aT[kk][ty * 4]);
      const float4 b4 = *reinterpret_cast<const float4*>(&bT[kk][tx * 4]);
      fma16(acc, a4, b4);
    }
  }
  const float4 bi = *reinterpret_cast<const float4*>(bo + tx * 4);
#pragma unroll
  for (int i = 0; i < 4; ++i) {
    float4 v;
    v.x = acc[i][0] + bi.x;
    v.y = acc[i][1] + bi.y;
    v.z = acc[i][2] + bi.z;
    v.w = acc[i][3] + bi.w;
    *reinterpret_cast<float4*>(out + (size_t)(p0 + ty * 4 + i) * DIM_ + tx * 4) = v;
  }
}

extern "C" void kernel_launch(void* const* d_in, const int* in_sizes, int n_in,
                              void* d_out, int out_size, void* d_ws, size_t ws_size,
                              hipStream_t stream) {
  const float* x    = (const float*)d_in[0];
  const float* temp = (const float*)d_in[1];
  const float* Wx   = (const float*)d_in[2];
  const float* bx   = (const float*)d_in[3];
  const float* Wfx  = (const float*)d_in[4];
  const float* bfx  = (const float*)d_in[5];
  const float* Ws   = (const float*)d_in[6];
  const float* bs   = (const float*)d_in[7];
  const float* Wq   = (const float*)d_in[8];
  const float* Wk   = (const float*)d_in[9];
  const float* Wv   = (const float*)d_in[10];
  const float* Wo   = (const float*)d_in[11];
  const float* bo   = (const float*)d_in[12];
  float* out = (float*)d_out;

  // workspace (~81.5 MB)
  char* p = (char*)d_ws;
  ushort* WTH = (ushort*)p; p += (size_t)9 * 1024 * 128 * 2;   // 2359296 B
  ushort* WTL = (ushort*)p; p += (size_t)9 * 1024 * 128 * 2;
  ushort* XPH = (ushort*)p; p += (size_t)PW_ * PW_ * 128 * 2;  // 4326400 B
  ushort* XPL = (ushort*)p; p += (size_t)PW_ * PW_ * 128 * 2;
  float* XW  = (float*)p; p += (size_t)N_ * INNER_ * 4;        // 33554432 B
  float* FXO = (float*)p; p += (size_t)N_ * INNER_ * 4;
  float* WoT = (float*)p; p += (size_t)INNER_ * DIM_ * 4;
  float* TOK = (float*)p; p += (size_t)B_ * HEADS_ * G_ * DH_ * 4;
  float* NRM = (float*)p; p += (size_t)B_ * HEADS_ * G_ * 4;
  float* OSL = (float*)p; p += (size_t)HEADS_ * G_ * DH_ * 4;
  float* QKV = (float*)p; p += (size_t)3 * HEADS_ * G_ * DH_ * 4;

  hipMemsetAsync(TOK, 0, (size_t)(B_ * HEADS_ * G_ * DH_ + B_ * HEADS_ * G_) * sizeof(float), stream);
  wprep_kernel<<<4608, 256, 0, stream>>>(Wx, Wfx, WTH, WTL);
  transpose_wo_kernel<<<256, 256, 0, stream>>>(Wo, WoT);

  for (int b = 0; b < B_; ++b) {
    const float* xb = x + (size_t)b * N_ * DIM_;
    float* outb = out + (size_t)b * N_ * DIM_;
    float* tokb = TOK + (size_t)b * HEADS_ * G_ * DH_;
    float* nrmb = NRM + (size_t)b * HEADS_ * G_;

    pad_split_kernel<<<8450, 256, 0, stream>>>(xb, XPH, XPL);
    conv_mfma_kernel<<<dim3(128, 8), 256, 0, stream>>>(XPH, XPL, WTH, WTL, bx, bfx, XW, FXO);
    slice_kernel<<<512, 256, 0, stream>>>(XW, FXO, Ws, bs, temp, tokb, nrmb);
    qkv_kernel<<<8, 256, 0, stream>>>(tokb, nrmb, Wq, Wk, Wv, QKV);
    attn_kernel<<<8, 256, 0, stream>>>(QKV, OSL);
    scatter_kernel<<<2048, 256, 0, stream>>>(XW, OSL, FXO);
    out_gemm_kernel<<<512, 256, 0, stream>>>(FXO, WoT, bo, outb);
  }
}

// Round 4
// 1395.709 us; speedup vs baseline: 2.1758x; 1.0839x over previous
//
#include <hip/hip_runtime.h>
#include <hip/hip_bf16.h>
#include <math.h>

#define B_ 4
#define H_ 128
#define W_ 128
#define DIM_ 128
#define HEADS_ 8
#define DH_ 64
#define G_ 64
#define INNER_ 512
#define N_ 16384
#define PW_ 130  // padded H/W

typedef __attribute__((ext_vector_type(8))) short sh8;
typedef __attribute__((ext_vector_type(4))) float vf4;

__device__ __forceinline__ void gload16(const void* g, void* l) {
  __builtin_amdgcn_global_load_lds((const __attribute__((address_space(1))) void*)g,
                                   (__attribute__((address_space(3))) void*)l, 16, 0, 0);
}

__device__ __forceinline__ void split_bf16(float v, ushort& h, ushort& l) {
  __hip_bfloat16 hb = __float2bfloat16(v);
  float hf = __bfloat162float(hb);
  __hip_bfloat16 lb = __float2bfloat16(v - hf);
  h = *reinterpret_cast<ushort*>(&hb);
  l = *reinterpret_cast<ushort*>(&lb);
}

// ---- prep: pad one batch of x into hi/lo bf16 [130][130][128], zero border ----
__global__ __launch_bounds__(256) void pad_split_kernel(const float* __restrict__ x,
                                                        ushort* __restrict__ xph,
                                                        ushort* __restrict__ xpl) {
  int idx = blockIdx.x * 256 + threadIdx.x;
  if (idx >= PW_ * PW_ * DIM_) return;
  const int c = idx & 127;
  const int px = (idx >> 7) % PW_;
  const int py = (idx >> 7) / PW_;
  float v = 0.0f;
  if (py >= 1 && py <= H_ && px >= 1 && px <= W_)
    v = x[(((size_t)(py - 1)) * W_ + (px - 1)) * DIM_ + c];
  split_bf16(v, xph[idx], xpl[idx]);
}

// ---- prep: combined conv weights -> [9][1024][128] hi/lo bf16 (oc-major, c contiguous) ----
__global__ __launch_bounds__(256) void wprep_kernel(const float* __restrict__ Wx,
                                                    const float* __restrict__ Wfx,
                                                    ushort* __restrict__ wth,
                                                    ushort* __restrict__ wtl) {
  int idx = blockIdx.x * 256 + threadIdx.x;
  if (idx >= 9 * 1024 * DIM_) return;
  const int c = idx & 127;
  const int oc = (idx >> 7) & 1023;
  const int tap = idx >> 17;
  float v;
  if (oc < INNER_) v = Wx[((size_t)oc * DIM_ + c) * 9 + tap];
  else             v = Wfx[((size_t)(oc - INNER_) * DIM_ + c) * 9 + tap];
  split_bf16(v, wth[idx], wtl[idx]);
}

// ---- fused bf16x3 MFMA conv: one batch, BOTH convs (N=1024 combined) ----
__global__ __launch_bounds__(256) void conv_mfma_kernel(
    const ushort* __restrict__ xph, const ushort* __restrict__ xpl,
    const ushort* __restrict__ wth, const ushort* __restrict__ wtl,
    const float* __restrict__ bx, const float* __restrict__ bfx,
    float* __restrict__ xw, float* __restrict__ fxo) {
  __shared__ __align__(16) ushort lds[16384];  // 32 KB
  const int t = threadIdx.x;
  const int lane = t & 63;
  const int wid = t >> 6;
  const int wm = wid & 1, wn = wid >> 1;
  const int y = blockIdx.x;
  const int n0 = blockIdx.y * 128;

  const int col = lane & 15;
  const int quad = lane >> 4;

  const int pixs = t & 127;
  const int kg = t >> 7;
  const int goff0 = pixs * DIM_ + kg * 8;
  const int goff1 = goff0 + 16;
  ushort* l0 = lds + t * 8;
  ushort* l1 = lds + 2048 + t * 8;

  const int a_rd = quad * 1024 + (wm * 64 + col) * 8;
  const int b_rd = quad * 1024 + (wn * 64 + col) * 8;

  vf4 acc[4][4];
#pragma unroll
  for (int i = 0; i < 4; ++i)
#pragma unroll
    for (int j = 0; j < 4; ++j) acc[i][j] = vf4{0.f, 0.f, 0.f, 0.f};

  for (int tap = 0; tap < 9; ++tap) {
    const int ky = tap / 3, kx = tap % 3;
    const ushort* aH = xph + ((size_t)(y + ky) * PW_ + kx) * DIM_;
    const ushort* aL = xpl + ((size_t)(y + ky) * PW_ + kx) * DIM_;
    const ushort* bH = wth + ((size_t)tap * 1024 + n0) * DIM_;
    const ushort* bL = wtl + ((size_t)tap * 1024 + n0) * DIM_;
    for (int c0 = 0; c0 < DIM_; c0 += 32) {
      __syncthreads();
      gload16(aH + c0 + goff0, l0);
      gload16(aH + c0 + goff1, l1);
      gload16(aL + c0 + goff0, l0 + 4096);
      gload16(aL + c0 + goff1, l1 + 4096);
      gload16(bH + c0 + goff0, l0 + 8192);
      gload16(bH + c0 + goff1, l1 + 8192);
      gload16(bL + c0 + goff0, l0 + 12288);
      gload16(bL + c0 + goff1, l1 + 12288);
      __syncthreads();
      sh8 ah[4], al[4], bh[4], bl[4];
#pragma unroll
      for (int i = 0; i < 4; ++i) {
        ah[i] = *reinterpret_cast<const sh8*>(lds + a_rd + i * 128);
        al[i] = *reinterpret_cast<const sh8*>(lds + 4096 + a_rd + i * 128);
        bh[i] = *reinterpret_cast<const sh8*>(lds + 8192 + b_rd + i * 128);
        bl[i] = *reinterpret_cast<const sh8*>(lds + 12288 + b_rd + i * 128);
      }
#pragma unroll
      for (int i = 0; i < 4; ++i)
#pragma unroll
        for (int j = 0; j < 4; ++j) {
          acc[i][j] = __builtin_amdgcn_mfma_f32_16x16x32_bf16(ah[i], bh[j], acc[i][j], 0, 0, 0);
          acc[i][j] = __builtin_amdgcn_mfma_f32_16x16x32_bf16(ah[i], bl[j], acc[i][j], 0, 0, 0);
          acc[i][j] = __builtin_amdgcn_mfma_f32_16x16x32_bf16(al[i], bh[j], acc[i][j], 0, 0, 0);
        }
    }
  }
  const bool first = (blockIdx.y < 4);
  float* outp = first ? xw : fxo;
  const float* bb = first ? bx : bfx;
  const int ocbase = (blockIdx.y & 3) * 128 + wn * 64 + col;
#pragma unroll
  for (int j = 0; j < 4; ++j) {
    const int oc = ocbase + j * 16;
    const float bv = bb[oc];
#pragma unroll
    for (int i = 0; i < 4; ++i) {
#pragma unroll
      for (int r = 0; r < 4; ++r) {
        const int px = wm * 64 + i * 16 + quad * 4 + r;
        outp[((size_t)(y * W_ + px)) * INNER_ + oc] = acc[i][j][r] + bv;
      }
    }
  }
}

__device__ __forceinline__ void fma16(float (&acc)[4][4], const float4 a, const float4 b) {
  acc[0][0] = fmaf(a.x, b.x, acc[0][0]);
  acc[0][1] = fmaf(a.x, b.y, acc[0][1]);
  acc[0][2] = fmaf(a.x, b.z, acc[0][2]);
  acc[0][3] = fmaf(a.x, b.w, acc[0][3]);
  acc[1][0] = fmaf(a.y, b.x, acc[1][0]);
  acc[1][1] = fmaf(a.y, b.y, acc[1][1]);
  acc[1][2] = fmaf(a.y, b.z, acc[1][2]);
  acc[1][3] = fmaf(a.y, b.w, acc[1][3]);
  acc[2][0] = fmaf(a.z, b.x, acc[2][0]);
  acc[2][1] = fmaf(a.z, b.y, acc[2][1]);
  acc[2][2] = fmaf(a.z, b.z, acc[2][2]);
  acc[2][3] = fmaf(a.z, b.w, acc[2][3]);
  acc[3][0] = fmaf(a.w, b.x, acc[3][0]);
  acc[3][1] = fmaf(a.w, b.y, acc[3][1]);
  acc[3][2] = fmaf(a.w, b.z, acc[3][2]);
  acc[3][3] = fmaf(a.w, b.w, acc[3][3]);
}

// ONE batch. logits -> softmax -> packed hi/lo w in place over x_mid (uint32 per element),
// token + norm partials via atomics. grid 512, block 256.
__global__ __launch_bounds__(256) void slice_kernel(float* __restrict__ xw,
                                                    const float* __restrict__ fxg,
                                                    const float* __restrict__ Ws,
                                                    const float* __restrict__ bs,
                                                    const float* __restrict__ temperature,
                                                    float* __restrict__ tok,
                                                    float* __restrict__ nrm) {
  __shared__ __align__(16) float xmT[64][68];
  __shared__ __align__(16) float WsT[64][68];
  __shared__ __align__(16) float fxl[64][68];
  __shared__ float bsl[64];
  float (*wl)[68] = xmT;
  unsigned int* xwp = reinterpret_cast<unsigned int*>(xw);

  const int t = threadIdx.x;
  const int sub = blockIdx.x & 63;
  const int h = blockIdx.x >> 6;
  const int nbase = sub * 256;
  const int tx = t & 15;
  const int ty = t >> 4;

  {
    const int cg = t & 15;
    const int gr = t >> 4;
#pragma unroll
    for (int r = 0; r < 4; ++r) {
      const int gg = gr + r * 16;
      const float4 v = *reinterpret_cast<const float4*>(Ws + (size_t)gg * DH_ + cg * 4);
      WsT[cg * 4 + 0][gg] = v.x;
      WsT[cg * 4 + 1][gg] = v.y;
      WsT[cg * 4 + 2][gg] = v.z;
      WsT[cg * 4 + 3][gg] = v.w;
    }
    if (t < 64) bsl[t] = bs[t];
  }
  float tmp = temperature[h];
  tmp = fminf(fmaxf(tmp, 0.1f), 5.0f);
  const float invt = 1.0f / tmp;

  float acc2[4][4] = {};
  float snrm = 0.0f;

  for (int s = 0; s < 4; ++s) {
    const int n0 = nbase + s * 64;
    __syncthreads();
    {
      const int cg = t & 15;
      const int nr = t >> 4;
#pragma unroll
      for (int r = 0; r < 4; ++r) {
        const int nn = nr + r * 16;
        const size_t rowoff = ((size_t)(n0 + nn)) * INNER_ + h * DH_ + cg * 4;
        const float4 v = *reinterpret_cast<const float4*>(xw + rowoff);
        xmT[cg * 4 + 0][nn] = v.x;
        xmT[cg * 4 + 1][nn] = v.y;
        xmT[cg * 4 + 2][nn] = v.z;
        xmT[cg * 4 + 3][nn] = v.w;
        *reinterpret_cast<float4*>(&fxl[nn][cg * 4]) =
            *reinterpret_cast<const float4*>(fxg + rowoff);
      }
    }
    __syncthreads();
    float lacc[4][4] = {};
#pragma unroll
    for (int kk = 0; kk < 64; ++kk) {
      const float4 a4 = *reinterpret_cast<const float4*>(&xmT[kk][ty * 4]);
      const float4 b4 = *reinterpret_cast<const float4*>(&WsT[kk][tx * 4]);
      fma16(lacc, a4, b4);
    }
    __syncthreads();
#pragma unroll
    for (int i = 0; i < 4; ++i)
#pragma unroll
      for (int j = 0; j < 4; ++j)
        wl[ty * 4 + i][tx * 4 + j] = (lacc[i][j] + bsl[tx * 4 + j]) * invt;
    __syncthreads();
    if (t < 64) {
      float m = -3.4e38f;
#pragma unroll
      for (int g = 0; g < 64; ++g) m = fmaxf(m, wl[t][g]);
      float ssum = 0.0f;
#pragma unroll
      for (int g = 0; g < 64; ++g) {
        const float e = __expf(wl[t][g] - m);
        wl[t][g] = e;
        ssum += e;
      }
      const float inv = 1.0f / ssum;
#pragma unroll
      for (int g = 0; g < 64; ++g) wl[t][g] *= inv;
    }
    __syncthreads();
    // write w back packed (hi<<16)|lo
    {
      const int gg = t & 15;
      const int nr = t >> 4;
#pragma unroll
      for (int r = 0; r < 4; ++r) {
        const int nn = nr + r * 16;
        uint4 pk;
        unsigned int* pp = reinterpret_cast<unsigned int*>(&pk);
#pragma unroll
        for (int j = 0; j < 4; ++j) {
          ushort hh, ll;
          split_bf16(wl[nn][gg * 4 + j], hh, ll);
          pp[j] = ((unsigned int)hh << 16) | (unsigned int)ll;
        }
        *reinterpret_cast<uint4*>(xwp + ((size_t)(n0 + nn)) * INNER_ + h * DH_ + gg * 4) = pk;
      }
    }
    if (t < 64) {
#pragma unroll
      for (int n = 0; n < 64; ++n) snrm += wl[n][t];
    }
#pragma unroll
    for (int kk = 0; kk < 64; ++kk) {
      const float4 a4 = *reinterpret_cast<const float4*>(&wl[kk][ty * 4]);
      const float4 b4 = *reinterpret_cast<const float4*>(&fxl[kk][tx * 4]);
      fma16(acc2, a4, b4);
    }
    __syncthreads();
  }
  float* tokp = tok + (size_t)h * G_ * DH_;
#pragma unroll
  for (int i = 0; i < 4; ++i)
#pragma unroll
    for (int j = 0; j < 4; ++j)
      atomicAdd(tokp + (size_t)(ty * 4 + i) * DH_ + tx * 4 + j, acc2[i][j]);
  if (t < 64) atomicAdd(nrm + (size_t)h * G_ + t, snrm);
}

// ONE batch. grid 8, block 256. qkv layout [m][h][g][d]
__global__ __launch_bounds__(256) void qkv_kernel(const float* __restrict__ tok,
                                                  const float* __restrict__ nrm,
                                                  const float* __restrict__ Wq,
                                                  const float* __restrict__ Wk,
                                                  const float* __restrict__ Wv,
                                                  float* __restrict__ qkv) {
  __shared__ float st[64][65];
  __shared__ float wb[64][65];
  const int t = threadIdx.x;
  const int h = blockIdx.x;
  for (int e = t; e < 4096; e += 256) {
    const int g = e >> 6;
    st[g][e & 63] = tok[(size_t)h * 4096 + e] / (nrm[(size_t)h * 64 + g] + 1e-5f);
  }
  const float* Wp[3] = {Wq, Wk, Wv};
  for (int m = 0; m < 3; ++m) {
    __syncthreads();
    for (int e = t; e < 4096; e += 256) wb[e >> 6][e & 63] = Wp[m][e];
    __syncthreads();
    for (int e = t; e < 4096; e += 256) {
      const int g = e >> 6, d = e & 63;
      float s = 0.0f;
#pragma unroll
      for (int c = 0; c < 64; ++c) s = fmaf(st[g][c], wb[d][c], s);
      qkv[((size_t)m * HEADS_ + h) * 4096 + e] = s;
    }
  }
}

// ONE batch. grid 8, block 256.
__global__ __launch_bounds__(256) void attn_kernel(const float* __restrict__ qkv,
                                                   float* __restrict__ osl) {
  __shared__ float X[64][65];
  __shared__ float Y[64][65];
  __shared__ float Z[64][65];
  const int t = threadIdx.x;
  const int h = blockIdx.x;
  for (int e = t; e < 4096; e += 256) {
    X[e >> 6][e & 63] = qkv[(size_t)h * 4096 + e];
    Y[e >> 6][e & 63] = qkv[((size_t)HEADS_ + h) * 4096 + e];
  }
  __syncthreads();
  for (int e = t; e < 4096; e += 256) {
    const int g = e >> 6, kx = e & 63;
    float s = 0.0f;
#pragma unroll
    for (int d = 0; d < 64; ++d) s = fmaf(X[g][d], Y[kx][d], s);
    Z[g][kx] = s * 0.125f;
  }
  __syncthreads();
  for (int e = t; e < 4096; e += 256)
    X[e >> 6][e & 63] = qkv[((size_t)2 * HEADS_ + h) * 4096 + e];
  if (t < 64) {
    float m = -3.4e38f;
#pragma unroll
    for (int k = 0; k < 64; ++k) m = fmaxf(m, Z[t][k]);
    float ssum = 0.0f;
#pragma unroll
    for (int k = 0; k < 64; ++k) {
      const float e2 = __expf(Z[t][k] - m);
      Z[t][k] = e2;
      ssum += e2;
    }
    const float inv = 1.0f / ssum;
#pragma unroll
    for (int k = 0; k < 64; ++k) Z[t][k] *= inv;
  }
  __syncthreads();
  for (int e = t; e < 4096; e += 256) {
    const int g = e >> 6, d = e & 63;
    float s = 0.0f;
#pragma unroll
    for (int k = 0; k < 64; ++k) s = fmaf(Z[g][k], X[k][d], s);
    osl[(size_t)h * 4096 + e] = s;
  }
}

// ONE batch. Mcat[hg][o] = sum_d osl[hg][d] * Wo[o][h*64+d]; output tiled hi/lo
// [64 kg][128 o][8 kr]. grid 256, block 256.
__global__ __launch_bounds__(256) void outmat_kernel(const float* __restrict__ osl,
                                                     const float* __restrict__ Wo,
                                                     ushort* __restrict__ mht,
                                                     ushort* __restrict__ mlt) {
  const int idx = blockIdx.x * 256 + threadIdx.x;  // 65536
  const int o = idx & 127;
  const int hg = idx >> 7;
  const int h = hg >> 6;
  const float* op = osl + (size_t)hg * 64;
  const float* wp2 = Wo + (size_t)o * INNER_ + h * 64;
  float s = 0.0f;
#pragma unroll
  for (int d = 0; d < 64; ++d) s = fmaf(op[d], wp2[d], s);
  ushort hh, ll;
  split_bf16(s, hh, ll);
  const int kg = hg >> 3, kr = hg & 7;
  mht[((size_t)kg * 128 + o) * 8 + kr] = hh;
  mlt[((size_t)kg * 128 + o) * 8 + kr] = ll;
}

// ONE batch. Fused scatter+projection: out[n][o] = sum_k w[n][k] * Mcat[k][o] + bo[o].
// A = packed w (uint32 hi/lo) [N][512]; B = tiled Mcat hi/lo. bf16x3 MFMA.
// grid 256 (M-tile 64), block 256 (4 waves, 2m x 2n).
__global__ __launch_bounds__(256) void fused_out_kernel(
    const unsigned int* __restrict__ wp,  // packed w
    const ushort* __restrict__ mht,       // [64kg][128o][8]
    const ushort* __restrict__ mlt,
    const float* __restrict__ bo,
    float* __restrict__ out) {
  // ushort offsets: Ah 0 (8KB), Al 4096, Bh 8192 (16KB), Bl 16384. total 48 KB.
  __shared__ __align__(16) ushort lds[24576];
  const int t = threadIdx.x;
  const int lane = t & 63;
  const int wid = t >> 6;
  const int wm = wid & 1, wn = wid >> 1;
  const int col = lane & 15, quad = lane >> 4;
  const int n0 = blockIdx.x * 64;

  vf4 acc[2][4];
#pragma unroll
  for (int m = 0; m < 2; ++m)
#pragma unroll
    for (int n = 0; n < 4; ++n) acc[m][n] = vf4{0.f, 0.f, 0.f, 0.f};

  for (int kc = 0; kc < 8; ++kc) {
    __syncthreads();
    // A stage: rows = pix*8+kg (512 rows of 16B per plane); XOR-swizzled dest.
#pragma unroll
    for (int r = 0; r < 2; ++r) {
      const int row = r * 256 + t;
      const int pix = row >> 3, kg2 = row & 7;
      const unsigned int* gp = wp + (size_t)(n0 + pix) * INNER_ + kc * 64 + kg2 * 8;
      const uint4 p0 = *reinterpret_cast<const uint4*>(gp);
      const uint4 p1 = *reinterpret_cast<const uint4*>(gp + 4);
      unsigned int u[8] = {p0.x, p0.y, p0.z, p0.w, p1.x, p1.y, p1.z, p1.w};
      sh8 hv, lv;
#pragma unroll
      for (int j = 0; j < 8; ++j) {
        hv[j] = (short)(u[j] >> 16);
        lv[j] = (short)(u[j] & 0xffff);
      }
      const int drow = pix * 8 + (kg2 ^ (pix & 7));
      *reinterpret_cast<sh8*>(lds + drow * 8) = hv;
      *reinterpret_cast<sh8*>(lds + 4096 + drow * 8) = lv;
    }
    // B stage: gload16 from pre-tiled Mcat (16 KB per plane per chunk)
#pragma unroll
    for (int r = 0; r < 4; ++r) {
      gload16(mht + (size_t)kc * 8192 + ((size_t)r * 256 + t) * 8, lds + 8192 + r * 2048 + t * 8);
      gload16(mlt + (size_t)kc * 8192 + ((size_t)r * 256 + t) * 8, lds + 16384 + r * 2048 + t * 8);
    }
    __syncthreads();
#pragma unroll
    for (int kk = 0; kk < 2; ++kk) {
      const int kg2 = kk * 4 + quad;
      sh8 ah[2], al[2], bh[4], bl[4];
#pragma unroll
      for (int m = 0; m < 2; ++m) {
        const int pix = wm * 32 + m * 16 + col;
        const int drow = pix * 8 + (kg2 ^ (pix & 7));
        ah[m] = *reinterpret_cast<const sh8*>(lds + drow * 8);
        al[m] = *reinterpret_cast<const sh8*>(lds + 4096 + drow * 8);
      }
#pragma unroll
      for (int n = 0; n < 4; ++n) {
        const int o = wn * 64 + n * 16 + col;
        bh[n] = *reinterpret_cast<const sh8*>(lds + 8192 + ((size_t)kg2 * 128 + o) * 8);
        bl[n] = *reinterpret_cast<const sh8*>(lds + 16384 + ((size_t)kg2 * 128 + o) * 8);
      }
#pragma unroll
      for (int m = 0; m < 2; ++m)
#pragma unroll
        for (int n = 0; n < 4; ++n) {
          acc[m][n] = __builtin_amdgcn_mfma_f32_16x16x32_bf16(ah[m], bh[n], acc[m][n], 0, 0, 0);
          acc[m][n] = __builtin_amdgcn_mfma_f32_16x16x32_bf16(ah[m], bl[n], acc[m][n], 0, 0, 0);
          acc[m][n] = __builtin_amdgcn_mfma_f32_16x16x32_bf16(al[m], bh[n], acc[m][n], 0, 0, 0);
        }
    }
  }
  // epilogue: C/D col=lane&15 (o), row=quad*4+r (pixel)
#pragma unroll
  for (int n = 0; n < 4; ++n) {
    const int o = wn * 64 + n * 16 + col;
    const float bv = bo[o];
#pragma unroll
    for (int m = 0; m < 2; ++m) {
#pragma unroll
      for (int r = 0; r < 4; ++r) {
        const int pix = wm * 32 + m * 16 + quad * 4 + r;
        out[(size_t)(n0 + pix) * DIM_ + o] = acc[m][n][r] + bv;
      }
    }
  }
}

extern "C" void kernel_launch(void* const* d_in, const int* in_sizes, int n_in,
                              void* d_out, int out_size, void* d_ws, size_t ws_size,
                              hipStream_t stream) {
  const float* x    = (const float*)d_in[0];
  const float* temp = (const float*)d_in[1];
  const float* Wx   = (const float*)d_in[2];
  const float* bx   = (const float*)d_in[3];
  const float* Wfx  = (const float*)d_in[4];
  const float* bfx  = (const float*)d_in[5];
  const float* Ws   = (const float*)d_in[6];
  const float* bs   = (const float*)d_in[7];
  const float* Wq   = (const float*)d_in[8];
  const float* Wk   = (const float*)d_in[9];
  const float* Wv   = (const float*)d_in[10];
  const float* Wo   = (const float*)d_in[11];
  const float* bo   = (const float*)d_in[12];
  float* out = (float*)d_out;

  char* p = (char*)d_ws;
  ushort* WTH = (ushort*)p; p += (size_t)9 * 1024 * 128 * 2;
  ushort* WTL = (ushort*)p; p += (size_t)9 * 1024 * 128 * 2;
  ushort* XPH = (ushort*)p; p += (size_t)PW_ * PW_ * 128 * 2;
  ushort* XPL = (ushort*)p; p += (size_t)PW_ * PW_ * 128 * 2;
  float* XW  = (float*)p; p += (size_t)N_ * INNER_ * 4;   // x_mid -> packed w
  float* FXO = (float*)p; p += (size_t)N_ * INNER_ * 4;   // fx_mid
  float* TOK = (float*)p; p += (size_t)B_ * HEADS_ * G_ * DH_ * 4;
  float* NRM = (float*)p; p += (size_t)B_ * HEADS_ * G_ * 4;
  float* OSL = (float*)p; p += (size_t)HEADS_ * G_ * DH_ * 4;
  float* QKV = (float*)p; p += (size_t)3 * HEADS_ * G_ * DH_ * 4;
  ushort* MHT = (ushort*)p; p += (size_t)INNER_ * DIM_ * 2;
  ushort* MLT = (ushort*)p; p += (size_t)INNER_ * DIM_ * 2;

  hipMemsetAsync(TOK, 0, (size_t)(B_ * HEADS_ * G_ * DH_ + B_ * HEADS_ * G_) * sizeof(float), stream);
  wprep_kernel<<<4608, 256, 0, stream>>>(Wx, Wfx, WTH, WTL);

  for (int b = 0; b < B_; ++b) {
    const float* xb = x + (size_t)b * N_ * DIM_;
    float* outb = out + (size_t)b * N_ * DIM_;
    float* tokb = TOK + (size_t)b * HEADS_ * G_ * DH_;
    float* nrmb = NRM + (size_t)b * HEADS_ * G_;

    pad_split_kernel<<<8450, 256, 0, stream>>>(xb, XPH, XPL);
    conv_mfma_kernel<<<dim3(128, 8), 256, 0, stream>>>(XPH, XPL, WTH, WTL, bx, bfx, XW, FXO);
    slice_kernel<<<512, 256, 0, stream>>>(XW, FXO, Ws, bs, temp, tokb, nrmb);
    qkv_kernel<<<8, 256, 0, stream>>>(tokb, nrmb, Wq, Wk, Wv, QKV);
    attn_kernel<<<8, 256, 0, stream>>>(QKV, OSL);
    outmat_kernel<<<256, 256, 0, stream>>>(OSL, Wo, MHT, MLT);
    fused_out_kernel<<<256, 256, 0, stream>>>((const unsigned int*)XW, MHT, MLT, bo, outb);
  }
}

// Round 5
// 1322.321 us; speedup vs baseline: 2.2965x; 1.0555x over previous
//
#include <hip/hip_runtime.h>
#include <hip/hip_bf16.h>
#include <math.h>

#define B_ 4
#define H_ 128
#define W_ 128
#define DIM_ 128
#define HEADS_ 8
#define DH_ 64
#define G_ 64
#define INNER_ 512
#define N_ 16384
#define PW_ 130  // padded H/W

typedef __attribute__((ext_vector_type(8))) short sh8;
typedef __attribute__((ext_vector_type(4))) float vf4;

__device__ __forceinline__ void gload16(const void* g, void* l) {
  __builtin_amdgcn_global_load_lds((const __attribute__((address_space(1))) void*)g,
                                   (__attribute__((address_space(3))) void*)l, 16, 0, 0);
}

__device__ __forceinline__ void split_bf16(float v, ushort& h, ushort& l) {
  __hip_bfloat16 hb = __float2bfloat16(v);
  float hf = __bfloat162float(hb);
  __hip_bfloat16 lb = __float2bfloat16(v - hf);
  h = *reinterpret_cast<ushort*>(&hb);
  l = *reinterpret_cast<ushort*>(&lb);
}

// ---- prep: pad one batch of x into hi/lo bf16 [130][130][128], zero border ----
__global__ __launch_bounds__(256) void pad_split_kernel(const float* __restrict__ x,
                                                        ushort* __restrict__ xph,
                                                        ushort* __restrict__ xpl) {
  int idx = blockIdx.x * 256 + threadIdx.x;
  if (idx >= PW_ * PW_ * DIM_) return;
  const int c = idx & 127;
  const int px = (idx >> 7) % PW_;
  const int py = (idx >> 7) / PW_;
  float v = 0.0f;
  if (py >= 1 && py <= H_ && px >= 1 && px <= W_)
    v = x[(((size_t)(py - 1)) * W_ + (px - 1)) * DIM_ + c];
  split_bf16(v, xph[idx], xpl[idx]);
}

// ---- prep: fx-branch weights -> wth/wtl[tap][512+oc][c] ----
__global__ __launch_bounds__(256) void wfx_kernel(const float* __restrict__ Wfx,
                                                  ushort* __restrict__ wth,
                                                  ushort* __restrict__ wtl) {
  int idx = blockIdx.x * 256 + threadIdx.x;
  if (idx >= 9 * 512 * DIM_) return;
  const int c = idx & 127;
  const int oc = (idx >> 7) & 511;
  const int tap = idx >> 16;
  float v = Wfx[((size_t)oc * DIM_ + c) * 9 + tap];
  ushort hh, ll;
  split_bf16(v, hh, ll);
  const size_t o = ((size_t)tap * 1024 + 512 + oc) * DIM_ + c;
  wth[o] = hh;
  wtl[o] = ll;
}

// ---- prep: composed x-branch weights: Wc[h*64+g][c][tap] = sum_c' Ws[g][c']*Wx[h*64+c'][c][tap] / temp_h
// also composed bias bc. grid dim3(9 taps, 8 heads), block 256.
__global__ __launch_bounds__(256) void wcomp_kernel(const float* __restrict__ Wx,
                                                    const float* __restrict__ Ws,
                                                    const float* __restrict__ bx,
                                                    const float* __restrict__ bs,
                                                    const float* __restrict__ temperature,
                                                    ushort* __restrict__ wth,
                                                    ushort* __restrict__ wtl,
                                                    float* __restrict__ bc) {
  __shared__ float WxL[64][128];
  __shared__ float WsL[64][64];
  const int t = threadIdx.x;
  const int tap = blockIdx.x, h = blockIdx.y;
  for (int e = t; e < 8192; e += 256) {
    const int c2 = e >> 7, c = e & 127;
    WxL[c2][c] = Wx[((size_t)(h * 64 + c2) * DIM_ + c) * 9 + tap];
  }
  for (int e = t; e < 4096; e += 256) WsL[e >> 6][e & 63] = Ws[e];
  float tmp = fminf(fmaxf(temperature[h], 0.1f), 5.0f);
  const float invt = 1.0f / tmp;
  __syncthreads();
  for (int e = t; e < 8192; e += 256) {
    const int gg = e >> 7, c = e & 127;
    float s = 0.f;
#pragma unroll
    for (int c2 = 0; c2 < 64; ++c2) s = fmaf(WsL[gg][c2], WxL[c2][c], s);
    s *= invt;
    ushort hh, ll;
    split_bf16(s, hh, ll);
    const size_t o = ((size_t)tap * 1024 + h * 64 + gg) * DIM_ + c;
    wth[o] = hh;
    wtl[o] = ll;
  }
  if (tap == 0 && t < 64) {
    float s = 0.f;
#pragma unroll
    for (int c2 = 0; c2 < 64; ++c2) s = fmaf(Ws[t * 64 + c2], bx[h * 64 + c2], s);
    bc[h * 64 + t] = (s + bs[t]) * invt;
  }
}

// ---- prep: Mqk[c][c'] = scale * sum_d Wq[d][c]*Wk[d][c']  (head-independent) ----
__global__ __launch_bounds__(256) void mqk_kernel(const float* __restrict__ Wq,
                                                  const float* __restrict__ Wk,
                                                  float* __restrict__ mqk) {
  const int idx = blockIdx.x * 256 + threadIdx.x;  // 4096
  const int c = idx >> 6, c2 = idx & 63;
  float s = 0.f;
#pragma unroll
  for (int d = 0; d < 64; ++d) s = fmaf(Wq[d * 64 + c], Wk[d * 64 + c2], s);
  mqk[idx] = s * 0.125f;
}

// ---- fused bf16x3 MFMA conv: one batch. y-tiles 0-3 emit LOGITS (Ws/temp folded),
// y-tiles 4-7 emit fx_mid. grid (128, 8), block 256 (4 waves). ----
__global__ __launch_bounds__(256, 3) void conv_mfma_kernel(
    const ushort* __restrict__ xph, const ushort* __restrict__ xpl,
    const ushort* __restrict__ wth, const ushort* __restrict__ wtl,
    const float* __restrict__ bc, const float* __restrict__ bfx,
    float* __restrict__ lg, float* __restrict__ fxo) {
  __shared__ __align__(16) ushort lds[16384];  // 32 KB
  const int t = threadIdx.x;
  const int lane = t & 63;
  const int wid = t >> 6;
  const int wm = wid & 1, wn = wid >> 1;
  const int y = blockIdx.x;
  const int n0 = blockIdx.y * 128;

  const int col = lane & 15;
  const int quad = lane >> 4;

  const int pixs = t & 127;
  const int kg = t >> 7;
  const int goff0 = pixs * DIM_ + kg * 8;
  const int goff1 = goff0 + 16;
  ushort* l0 = lds + t * 8;
  ushort* l1 = lds + 2048 + t * 8;

  const int a_rd = quad * 1024 + (wm * 64 + col) * 8;
  const int b_rd = quad * 1024 + (wn * 64 + col) * 8;

  vf4 acc[4][4];
#pragma unroll
  for (int i = 0; i < 4; ++i)
#pragma unroll
    for (int j = 0; j < 4; ++j) acc[i][j] = vf4{0.f, 0.f, 0.f, 0.f};

  for (int tap = 0; tap < 9; ++tap) {
    const int ky = tap / 3, kx = tap % 3;
    const ushort* aH = xph + ((size_t)(y + ky) * PW_ + kx) * DIM_;
    const ushort* aL = xpl + ((size_t)(y + ky) * PW_ + kx) * DIM_;
    const ushort* bH = wth + ((size_t)tap * 1024 + n0) * DIM_;
    const ushort* bL = wtl + ((size_t)tap * 1024 + n0) * DIM_;
    for (int c0 = 0; c0 < DIM_; c0 += 32) {
      __syncthreads();
      gload16(aH + c0 + goff0, l0);
      gload16(aH + c0 + goff1, l1);
      gload16(aL + c0 + goff0, l0 + 4096);
      gload16(aL + c0 + goff1, l1 + 4096);
      gload16(bH + c0 + goff0, l0 + 8192);
      gload16(bH + c0 + goff1, l1 + 8192);
      gload16(bL + c0 + goff0, l0 + 12288);
      gload16(bL + c0 + goff1, l1 + 12288);
      __syncthreads();
      // hoist B fragments (shared over i) to reduce live-register peak
      sh8 bh[4], bl[4];
#pragma unroll
      for (int j = 0; j < 4; ++j) {
        bh[j] = *reinterpret_cast<const sh8*>(lds + 8192 + b_rd + j * 128);
        bl[j] = *reinterpret_cast<const sh8*>(lds + 12288 + b_rd + j * 128);
      }
#pragma unroll
      for (int i = 0; i < 4; ++i) {
        const sh8 ah = *reinterpret_cast<const sh8*>(lds + a_rd + i * 128);
        const sh8 al = *reinterpret_cast<const sh8*>(lds + 4096 + a_rd + i * 128);
#pragma unroll
        for (int j = 0; j < 4; ++j) {
          acc[i][j] = __builtin_amdgcn_mfma_f32_16x16x32_bf16(ah, bh[j], acc[i][j], 0, 0, 0);
          acc[i][j] = __builtin_amdgcn_mfma_f32_16x16x32_bf16(ah, bl[j], acc[i][j], 0, 0, 0);
          acc[i][j] = __builtin_amdgcn_mfma_f32_16x16x32_bf16(al, bh[j], acc[i][j], 0, 0, 0);
        }
      }
    }
  }
  const bool first = (blockIdx.y < 4);
  float* outp = first ? lg : fxo;
  const float* bb = first ? bc : bfx;
  const int ocbase = (blockIdx.y & 3) * 128 + wn * 64 + col;
#pragma unroll
  for (int j = 0; j < 4; ++j) {
    const int oc = ocbase + j * 16;
    const float bv = bb[oc];
#pragma unroll
    for (int i = 0; i < 4; ++i) {
#pragma unroll
      for (int r = 0; r < 4; ++r) {
        const int px = wm * 64 + i * 16 + quad * 4 + r;
        outp[((size_t)(y * W_ + px)) * INNER_ + oc] = acc[i][j][r] + bv;
      }
    }
  }
}

__device__ __forceinline__ void fma16(float (&acc)[4][4], const float4 a, const float4 b) {
  acc[0][0] = fmaf(a.x, b.x, acc[0][0]);
  acc[0][1] = fmaf(a.x, b.y, acc[0][1]);
  acc[0][2] = fmaf(a.x, b.z, acc[0][2]);
  acc[0][3] = fmaf(a.x, b.w, acc[0][3]);
  acc[1][0] = fmaf(a.y, b.x, acc[1][0]);
  acc[1][1] = fmaf(a.y, b.y, acc[1][1]);
  acc[1][2] = fmaf(a.y, b.z, acc[1][2]);
  acc[1][3] = fmaf(a.y, b.w, acc[1][3]);
  acc[2][0] = fmaf(a.z, b.x, acc[2][0]);
  acc[2][1] = fmaf(a.z, b.y, acc[2][1]);
  acc[2][2] = fmaf(a.z, b.z, acc[2][2]);
  acc[2][3] = fmaf(a.z, b.w, acc[2][3]);
  acc[3][0] = fmaf(a.w, b.x, acc[3][0]);
  acc[3][1] = fmaf(a.w, b.y, acc[3][1]);
  acc[3][2] = fmaf(a.w, b.z, acc[3][2]);
  acc[3][3] = fmaf(a.w, b.w, acc[3][3]);
}

// ONE batch. Logits already scaled: softmax -> packed hi/lo w in place, token+norm
// partials via atomics. grid 512 (h, 256-px chunk), block 256.
__global__ __launch_bounds__(256) void slice_kernel(float* __restrict__ lg,
                                                    const float* __restrict__ fxg,
                                                    float* __restrict__ tok,
                                                    float* __restrict__ nrm) {
  __shared__ __align__(16) float wl[64][68];
  __shared__ __align__(16) float fxl[64][68];
  unsigned int* lgp = reinterpret_cast<unsigned int*>(lg);

  const int t = threadIdx.x;
  const int sub = blockIdx.x & 63;
  const int h = blockIdx.x >> 6;
  const int nbase = sub * 256;
  const int tx = t & 15;
  const int ty = t >> 4;

  float acc2[4][4] = {};
  float snrm = 0.0f;

  for (int s = 0; s < 4; ++s) {
    const int n0 = nbase + s * 64;
    __syncthreads();
    {
      const int cg = t & 15;
      const int nr = t >> 4;
#pragma unroll
      for (int r = 0; r < 4; ++r) {
        const int nn = nr + r * 16;
        const size_t rowoff = ((size_t)(n0 + nn)) * INNER_ + h * DH_ + cg * 4;
        *reinterpret_cast<float4*>(&wl[nn][cg * 4]) =
            *reinterpret_cast<const float4*>(lg + rowoff);
        *reinterpret_cast<float4*>(&fxl[nn][cg * 4]) =
            *reinterpret_cast<const float4*>(fxg + rowoff);
      }
    }
    __syncthreads();
    if (t < 64) {
      float m = -3.4e38f;
#pragma unroll
      for (int g = 0; g < 64; ++g) m = fmaxf(m, wl[t][g]);
      float ssum = 0.0f;
#pragma unroll
      for (int g = 0; g < 64; ++g) {
        const float e = __expf(wl[t][g] - m);
        wl[t][g] = e;
        ssum += e;
      }
      const float inv = 1.0f / ssum;
#pragma unroll
      for (int g = 0; g < 64; ++g) wl[t][g] *= inv;
    }
    __syncthreads();
    {
      const int gg = t & 15;
      const int nr = t >> 4;
#pragma unroll
      for (int r = 0; r < 4; ++r) {
        const int nn = nr + r * 16;
        uint4 pk;
        unsigned int* pp = reinterpret_cast<unsigned int*>(&pk);
#pragma unroll
        for (int j = 0; j < 4; ++j) {
          ushort hh, ll;
          split_bf16(wl[nn][gg * 4 + j], hh, ll);
          pp[j] = ((unsigned int)hh << 16) | (unsigned int)ll;
        }
        *reinterpret_cast<uint4*>(lgp + ((size_t)(n0 + nn)) * INNER_ + h * DH_ + gg * 4) = pk;
      }
    }
    if (t < 64) {
#pragma unroll
      for (int n = 0; n < 64; ++n) snrm += wl[n][t];
    }
#pragma unroll
    for (int kk = 0; kk < 64; ++kk) {
      const float4 a4 = *reinterpret_cast<const float4*>(&wl[kk][ty * 4]);
      const float4 b4 = *reinterpret_cast<const float4*>(&fxl[kk][tx * 4]);
      fma16(acc2, a4, b4);
    }
  }
  __syncthreads();
  float* tokp = tok + (size_t)h * G_ * DH_;
#pragma unroll
  for (int i = 0; i < 4; ++i)
#pragma unroll
    for (int j = 0; j < 4; ++j)
      atomicAdd(tokp + (size_t)(ty * 4 + i) * DH_ + tx * 4 + j, acc2[i][j]);
  if (t < 64) atomicAdd(nrm + (size_t)h * G_ + t, snrm);
}

// ONE batch. Fused qkv+attn+outmat per head. grid 8, block 256.
// st -> Y(=Mqk.st^T), V -> dots(reg) -> softmax -> PV -> Mcat (tiled hi/lo).
__global__ __launch_bounds__(256) void head_kernel(const float* __restrict__ tok,
                                                   const float* __restrict__ nrm,
                                                   const float* __restrict__ mqk,
                                                   const float* __restrict__ Wv,
                                                   const float* __restrict__ Wo,
                                                   ushort* __restrict__ mht,
                                                   ushort* __restrict__ mlt) {
  __shared__ float ST[64 * 65];  // st -> Zt (transposed attn weights)
  __shared__ float YL[64 * 64];  // Y -> outL
  __shared__ float VL[64 * 64];
  __shared__ float red[8][64];
  const int t = threadIdx.x;
  const int h = blockIdx.x;

  for (int e = t; e < 4096; e += 256) {
    const int g = e >> 6, c = e & 63;
    ST[g * 65 + c] = tok[(size_t)h * 4096 + e] / (nrm[h * 64 + g] + 1e-5f);
  }
  __syncthreads();
  for (int e = t; e < 4096; e += 256) {
    const int k = e >> 6, c = e & 63;
    float sy = 0.f, sv = 0.f;
    const float* mrow = mqk + c * 64;
    const float* wrow = Wv + c * 64;  // c doubles as d for V
#pragma unroll
    for (int c2 = 0; c2 < 64; ++c2) {
      const float st2 = ST[k * 65 + c2];
      sy = fmaf(mrow[c2], st2, sy);
      sv = fmaf(wrow[c2], st2, sv);
    }
    YL[k * 64 + c] = sy;
    VL[k * 64 + c] = sv;
  }
  __syncthreads();
  // dots in registers: thread (g = t&63, kp = t>>6) covers k in [kp*16, kp*16+16)
  const int g = t & 63, kp = t >> 6;
  float z[16];
#pragma unroll
  for (int j = 0; j < 16; ++j) z[j] = 0.f;
  for (int c = 0; c < 64; ++c) {
    const float sg = ST[g * 65 + c];
#pragma unroll
    for (int j = 0; j < 16; ++j) z[j] = fmaf(sg, YL[(kp * 16 + j) * 64 + c], z[j]);
  }
  float m = z[0];
#pragma unroll
  for (int j = 1; j < 16; ++j) m = fmaxf(m, z[j]);
  red[kp][g] = m;
  __syncthreads();
  m = fmaxf(fmaxf(red[0][g], red[1][g]), fmaxf(red[2][g], red[3][g]));
  float ssum = 0.f;
#pragma unroll
  for (int j = 0; j < 16; ++j) {
    z[j] = __expf(z[j] - m);
    ssum += z[j];
  }
  red[4 + kp][g] = ssum;
  __syncthreads();
  ssum = red[4][g] + red[5][g] + red[6][g] + red[7][g];
  const float inv = 1.f / ssum;
  // write transposed attn into ST space (all ST reads completed before syncs above)
#pragma unroll
  for (int j = 0; j < 16; ++j) ST[(kp * 16 + j) * 65 + g] = z[j] * inv;
  __syncthreads();
  // PV: outL[g][d] into YL space
  for (int e = t; e < 4096; e += 256) {
    const int gg = e >> 6, d = e & 63;
    float s = 0.f;
#pragma unroll
    for (int k = 0; k < 64; ++k) s = fmaf(ST[k * 65 + gg], VL[k * 64 + d], s);
    YL[gg * 64 + d] = s;
  }
  __syncthreads();
  // Mcat[h*64+g][o] = sum_d outL[g][d]*Wo[o][h*64+d]; write tiled hi/lo
  for (int e = t; e < 8192; e += 256) {
    const int o = e & 127, gg = e >> 7;
    float s = 0.f;
    const float* wrow = Wo + (size_t)o * INNER_ + h * 64;
#pragma unroll
    for (int d = 0; d < 64; ++d) s = fmaf(YL[gg * 64 + d], wrow[d], s);
    ushort hh, ll;
    split_bf16(s, hh, ll);
    const int hg = h * 64 + gg;
    const int kg2 = hg >> 3, kr = hg & 7;
    mht[((size_t)kg2 * 128 + o) * 8 + kr] = hh;
    mlt[((size_t)kg2 * 128 + o) * 8 + kr] = ll;
  }
}

// ONE batch. out[n][o] = sum_k w[n][k]*Mcat[k][o] + bo[o]; bf16x3 MFMA.
// grid 256 (64-px M-tiles), block 256.
__global__ __launch_bounds__(256) void fused_out_kernel(
    const unsigned int* __restrict__ wp,
    const ushort* __restrict__ mht,
    const ushort* __restrict__ mlt,
    const float* __restrict__ bo,
    float* __restrict__ out) {
  __shared__ __align__(16) ushort lds[24576];
  const int t = threadIdx.x;
  const int lane = t & 63;
  const int wid = t >> 6;
  const int wm = wid & 1, wn = wid >> 1;
  const int col = lane & 15, quad = lane >> 4;
  const int n0 = blockIdx.x * 64;

  vf4 acc[2][4];
#pragma unroll
  for (int m = 0; m < 2; ++m)
#pragma unroll
    for (int n = 0; n < 4; ++n) acc[m][n] = vf4{0.f, 0.f, 0.f, 0.f};

  for (int kc = 0; kc < 8; ++kc) {
    __syncthreads();
#pragma unroll
    for (int r = 0; r < 2; ++r) {
      const int row = r * 256 + t;
      const int pix = row >> 3, kg2 = row & 7;
      const unsigned int* gp = wp + (size_t)(n0 + pix) * INNER_ + kc * 64 + kg2 * 8;
      const uint4 p0 = *reinterpret_cast<const uint4*>(gp);
      const uint4 p1 = *reinterpret_cast<const uint4*>(gp + 4);
      unsigned int u[8] = {p0.x, p0.y, p0.z, p0.w, p1.x, p1.y, p1.z, p1.w};
      sh8 hv, lv;
#pragma unroll
      for (int j = 0; j < 8; ++j) {
        hv[j] = (short)(u[j] >> 16);
        lv[j] = (short)(u[j] & 0xffff);
      }
      const int drow = pix * 8 + (kg2 ^ (pix & 7));
      *reinterpret_cast<sh8*>(lds + drow * 8) = hv;
      *reinterpret_cast<sh8*>(lds + 4096 + drow * 8) = lv;
    }
#pragma unroll
    for (int r = 0; r < 4; ++r) {
      gload16(mht + (size_t)kc * 8192 + ((size_t)r * 256 + t) * 8, lds + 8192 + r * 2048 + t * 8);
      gload16(mlt + (size_t)kc * 8192 + ((size_t)r * 256 + t) * 8, lds + 16384 + r * 2048 + t * 8);
    }
    __syncthreads();
#pragma unroll
    for (int kk = 0; kk < 2; ++kk) {
      const int kg2 = kk * 4 + quad;
      sh8 ah[2], al[2], bh[4], bl[4];
#pragma unroll
      for (int m = 0; m < 2; ++m) {
        const int pix = wm * 32 + m * 16 + col;
        const int drow = pix * 8 + (kg2 ^ (pix & 7));
        ah[m] = *reinterpret_cast<const sh8*>(lds + drow * 8);
        al[m] = *reinterpret_cast<const sh8*>(lds + 4096 + drow * 8);
      }
#pragma unroll
      for (int n = 0; n < 4; ++n) {
        const int o = wn * 64 + n * 16 + col;
        bh[n] = *reinterpret_cast<const sh8*>(lds + 8192 + ((size_t)kg2 * 128 + o) * 8);
        bl[n] = *reinterpret_cast<const sh8*>(lds + 16384 + ((size_t)kg2 * 128 + o) * 8);
      }
#pragma unroll
      for (int m = 0; m < 2; ++m)
#pragma unroll
        for (int n = 0; n < 4; ++n) {
          acc[m][n] = __builtin_amdgcn_mfma_f32_16x16x32_bf16(ah[m], bh[n], acc[m][n], 0, 0, 0);
          acc[m][n] = __builtin_amdgcn_mfma_f32_16x16x32_bf16(ah[m], bl[n], acc[m][n], 0, 0, 0);
          acc[m][n] = __builtin_amdgcn_mfma_f32_16x16x32_bf16(al[m], bh[n], acc[m][n], 0, 0, 0);
        }
    }
  }
#pragma unroll
  for (int n = 0; n < 4; ++n) {
    const int o = wn * 64 + n * 16 + col;
    const float bv = bo[o];
#pragma unroll
    for (int m = 0; m < 2; ++m) {
#pragma unroll
      for (int r = 0; r < 4; ++r) {
        const int pix = wm * 32 + m * 16 + quad * 4 + r;
        out[(size_t)(n0 + pix) * DIM_ + o] = acc[m][n][r] + bv;
      }
    }
  }
}

extern "C" void kernel_launch(void* const* d_in, const int* in_sizes, int n_in,
                              void* d_out, int out_size, void* d_ws, size_t ws_size,
                              hipStream_t stream) {
  const float* x    = (const float*)d_in[0];
  const float* temp = (const float*)d_in[1];
  const float* Wx   = (const float*)d_in[2];
  const float* bx   = (const float*)d_in[3];
  const float* Wfx  = (const float*)d_in[4];
  const float* bfx  = (const float*)d_in[5];
  const float* Ws   = (const float*)d_in[6];
  const float* bs   = (const float*)d_in[7];
  const float* Wq   = (const float*)d_in[8];
  const float* Wk   = (const float*)d_in[9];
  const float* Wv   = (const float*)d_in[10];
  const float* Wo   = (const float*)d_in[11];
  const float* bo   = (const float*)d_in[12];
  float* out = (float*)d_out;

  char* p = (char*)d_ws;
  ushort* WTH = (ushort*)p; p += (size_t)9 * 1024 * 128 * 2;
  ushort* WTL = (ushort*)p; p += (size_t)9 * 1024 * 128 * 2;
  ushort* XPH = (ushort*)p; p += (size_t)PW_ * PW_ * 128 * 2;
  ushort* XPL = (ushort*)p; p += (size_t)PW_ * PW_ * 128 * 2;
  float* LG  = (float*)p; p += (size_t)N_ * INNER_ * 4;   // logits -> packed w
  float* FXO = (float*)p; p += (size_t)N_ * INNER_ * 4;   // fx_mid
  float* TOK = (float*)p; p += (size_t)B_ * HEADS_ * G_ * DH_ * 4;
  float* NRM = (float*)p; p += (size_t)B_ * HEADS_ * G_ * 4;
  float* MQK = (float*)p; p += (size_t)DH_ * DH_ * 4;
  float* BC  = (float*)p; p += (size_t)INNER_ * 4;
  ushort* MHT = (ushort*)p; p += (size_t)INNER_ * DIM_ * 2;
  ushort* MLT = (ushort*)p; p += (size_t)INNER_ * DIM_ * 2;

  hipMemsetAsync(TOK, 0, (size_t)(B_ * HEADS_ * G_ * DH_ + B_ * HEADS_ * G_) * sizeof(float), stream);
  wfx_kernel<<<2304, 256, 0, stream>>>(Wfx, WTH, WTL);
  wcomp_kernel<<<dim3(9, 8), 256, 0, stream>>>(Wx, Ws, bx, bs, temp, WTH, WTL, BC);
  mqk_kernel<<<16, 256, 0, stream>>>(Wq, Wk, MQK);

  for (int b = 0; b < B_; ++b) {
    const float* xb = x + (size_t)b * N_ * DIM_;
    float* outb = out + (size_t)b * N_ * DIM_;
    float* tokb = TOK + (size_t)b * HEADS_ * G_ * DH_;
    float* nrmb = NRM + (size_t)b * HEADS_ * G_;

    pad_split_kernel<<<8450, 256, 0, stream>>>(xb, XPH, XPL);
    conv_mfma_kernel<<<dim3(128, 8), 256, 0, stream>>>(XPH, XPL, WTH, WTL, BC, bfx, LG, FXO);
    slice_kernel<<<512, 256, 0, stream>>>(LG, FXO, tokb, nrmb);
    head_kernel<<<8, 256, 0, stream>>>(tokb, nrmb, MQK, Wv, Wo, MHT, MLT);
    fused_out_kernel<<<256, 256, 0, stream>>>((const unsigned int*)LG, MHT, MLT, bo, outb);
  }
}

// Round 7
// 1024.931 us; speedup vs baseline: 2.9629x; 1.2902x over previous
//
#include <hip/hip_runtime.h>
#include <hip/hip_bf16.h>
#include <math.h>

#define B_ 4
#define H_ 128
#define W_ 128
#define DIM_ 128
#define HEADS_ 8
#define DH_ 64
#define G_ 64
#define INNER_ 512
#define N_ 16384

typedef __attribute__((ext_vector_type(8))) short sh8;
typedef __attribute__((ext_vector_type(4))) float vf4;

// XPT tiled input layout (per plane): [row 0..129][c0 0..3][tile 0..519][8]
//   tile = kg*130 + px  (kg = channel-group of 8 within 32-chunk, px = padded col)
// slab per (row,c0) = 520*8 = 4160 shorts.  plane = 130*4*4160 = 2163200 shorts.
#define XPT_SLAB 4160
#define XPT_PLANE 2163200
// WT tiled weight layout (per plane): [tap 0..8][nt 0..7][c0 0..3][tile 0..511][8]
//   tile = kg*128 + oc(0..127), oc global = nt*128+oc.
#define WT_PLANE 1179648

__device__ __forceinline__ void gload16(const void* g, void* l) {
  __builtin_amdgcn_global_load_lds((const __attribute__((address_space(1))) void*)g,
                                   (__attribute__((address_space(3))) void*)l, 16, 0, 0);
}

__device__ __forceinline__ void split_bf16(float v, ushort& h, ushort& l) {
  __hip_bfloat16 hb = __float2bfloat16(v);
  float hf = __bfloat162float(hb);
  __hip_bfloat16 lb = __float2bfloat16(v - hf);
  h = *reinterpret_cast<ushort*>(&hb);
  l = *reinterpret_cast<ushort*>(&lb);
}

// ---- prep: pad+split one batch of x directly into XPT tiled hi/lo layout ----
__global__ __launch_bounds__(256) void pad_tile_kernel(const float* __restrict__ x,
                                                       ushort* __restrict__ xpth,
                                                       ushort* __restrict__ xptl) {
  const int idx = blockIdx.x * 256 + threadIdx.x;  // 2163200 exactly (8450 blocks)
  const int row = idx / (4 * XPT_SLAB);
  const int rem = idx % (4 * XPT_SLAB);
  const int c0i = rem / XPT_SLAB;
  const int t2 = rem % XPT_SLAB;
  const int tile = t2 >> 3, j = t2 & 7;
  const int kg = tile / 130, px = tile % 130;
  const int c = c0i * 32 + kg * 8 + j;
  float v = 0.0f;
  if (row >= 1 && row <= H_ && px >= 1 && px <= W_)
    v = x[((size_t)(row - 1) * W_ + (px - 1)) * DIM_ + c];
  ushort hh, ll;
  split_bf16(v, hh, ll);
  xpth[idx] = hh;
  xptl[idx] = ll;
}

// ---- prep: fx-branch weights into WT tiled layout (nt 4..7) ----
__global__ __launch_bounds__(256) void wfx_kernel(const float* __restrict__ Wfx,
                                                  ushort* __restrict__ wth,
                                                  ushort* __restrict__ wtl) {
  int idx = blockIdx.x * 256 + threadIdx.x;
  if (idx >= 9 * 512 * DIM_) return;
  const int c = idx & 127;
  const int ocf = (idx >> 7) & 511;
  const int tap = idx >> 16;
  float v = Wfx[((size_t)ocf * DIM_ + c) * 9 + tap];
  ushort hh, ll;
  split_bf16(v, hh, ll);
  const int nt = 4 + (ocf >> 7), oci = ocf & 127;
  const int c0i = c >> 5, kg = (c >> 3) & 3, j = c & 7;
  const size_t o = (((size_t)tap * 8 + nt) * 4 + c0i) * 4096 + ((size_t)kg * 128 + oci) * 8 + j;
  wth[o] = hh;
  wtl[o] = ll;
}

// ---- prep: composed x-branch weights (Ws/temp folded), WT tiled (nt 0..3) + bias bc ----
__global__ __launch_bounds__(256) void wcomp_kernel(const float* __restrict__ Wx,
                                                    const float* __restrict__ Ws,
                                                    const float* __restrict__ bx,
                                                    const float* __restrict__ bs,
                                                    const float* __restrict__ temperature,
                                                    ushort* __restrict__ wth,
                                                    ushort* __restrict__ wtl,
                                                    float* __restrict__ bc) {
  __shared__ float WxL[64][128];
  __shared__ float WsL[64][64];
  const int t = threadIdx.x;
  const int tap = blockIdx.x, h = blockIdx.y;
  for (int e = t; e < 8192; e += 256) {
    const int c2 = e >> 7, c = e & 127;
    WxL[c2][c] = Wx[((size_t)(h * 64 + c2) * DIM_ + c) * 9 + tap];
  }
  for (int e = t; e < 4096; e += 256) WsL[e >> 6][e & 63] = Ws[e];
  float tmp = fminf(fmaxf(temperature[h], 0.1f), 5.0f);
  const float invt = 1.0f / tmp;
  __syncthreads();
  for (int e = t; e < 8192; e += 256) {
    const int gg = e >> 7, c = e & 127;
    float s = 0.f;
#pragma unroll
    for (int c2 = 0; c2 < 64; ++c2) s = fmaf(WsL[gg][c2], WxL[c2][c], s);
    s *= invt;
    ushort hh, ll;
    split_bf16(s, hh, ll);
    const int ocp = h * 64 + gg;
    const int nt = ocp >> 7, oci = ocp & 127;
    const int c0i = c >> 5, kg = (c >> 3) & 3, j = c & 7;
    const size_t o = (((size_t)tap * 8 + nt) * 4 + c0i) * 4096 + ((size_t)kg * 128 + oci) * 8 + j;
    wth[o] = hh;
    wtl[o] = ll;
  }
  if (tap == 0 && t < 64) {
    float s = 0.f;
#pragma unroll
    for (int c2 = 0; c2 < 64; ++c2) s = fmaf(Ws[t * 64 + c2], bx[h * 64 + c2], s);
    bc[h * 64 + t] = (s + bs[t]) * invt;
  }
}

// ---- prep: Mqk[c][c'] = scale * sum_d Wq[d][c]*Wk[d][c'] ----
__global__ __launch_bounds__(256) void mqk_kernel(const float* __restrict__ Wq,
                                                  const float* __restrict__ Wk,
                                                  float* __restrict__ mqk) {
  const int idx = blockIdx.x * 256 + threadIdx.x;  // 4096
  const int c = idx >> 6, c2 = idx & 63;
  float s = 0.f;
#pragma unroll
  for (int d = 0; d < 64; ++d) s = fmaf(Wq[d * 64 + c], Wk[d * 64 + c2], s);
  mqk[idx] = s * 0.125f;
}

// ---- bf16x3 MFMA conv, contiguous staging + A-reuse across kx. one batch.
// grid (128 rows, 8 nt), block 256 (4 waves, 2x2). nt 0..3 -> logits, 4..7 -> fx_mid.
// NOTE: all global_load_lds transfers are FULL-BLOCK (256 lanes). The 64-short slab
// tail is staged with a predicated regular load+ds_write — divergent global_load_lds
// (partial wave) clobbered LDS with garbage in R6 (NaN).
__global__ __launch_bounds__(256) void conv_mfma_kernel(
    const ushort* __restrict__ xpth, const ushort* __restrict__ xptl,
    const ushort* __restrict__ wth, const ushort* __restrict__ wtl,
    const float* __restrict__ bc, const float* __restrict__ bfx,
    float* __restrict__ lg, float* __restrict__ fxo) {
  // shorts: Ah@0 (4160), Al@4160, Bh@8320 (4096), Bl@12416. total 33024 B.
  __shared__ __align__(16) ushort lds[16512];
  const int t = threadIdx.x;
  const int lane = t & 63;
  const int wid = t >> 6;
  const int wm = wid & 1, wn = wid >> 1;
  const int y = blockIdx.x;
  const int nt = blockIdx.y;
  const int col = lane & 15, quad = lane >> 4;

  vf4 acc[4][4];
#pragma unroll
  for (int i = 0; i < 4; ++i)
#pragma unroll
    for (int j = 0; j < 4; ++j) acc[i][j] = vf4{0.f, 0.f, 0.f, 0.f};

  for (int ky = 0; ky < 3; ++ky) {
    for (int c0i = 0; c0i < 4; ++c0i) {
      const size_t aoff = ((size_t)(y + ky) * 4 + c0i) * XPT_SLAB;
      __syncthreads();  // prior phase's LDS reads done
      // A stage: 4160 shorts/plane; two full-block gloads + predicated scalar tail
      gload16(xpth + aoff + t * 8, lds + t * 8);
      gload16(xpth + aoff + 2048 + t * 8, lds + 2048 + t * 8);
      gload16(xptl + aoff + t * 8, lds + 4160 + t * 8);
      gload16(xptl + aoff + 2048 + t * 8, lds + 4160 + 2048 + t * 8);
      if (t < 8) {
        *reinterpret_cast<sh8*>(lds + 4096 + t * 8) =
            *reinterpret_cast<const sh8*>(xpth + aoff + 4096 + t * 8);
        *reinterpret_cast<sh8*>(lds + 4160 + 4096 + t * 8) =
            *reinterpret_cast<const sh8*>(xptl + aoff + 4096 + t * 8);
      }
      for (int kx = 0; kx < 3; ++kx) {
        const int tap = ky * 3 + kx;
        const size_t boff = (((size_t)tap * 8 + nt) * 4 + c0i) * 4096;
        if (kx > 0) __syncthreads();  // prior kx's B reads done
        gload16(wth + boff + t * 8, lds + 8320 + t * 8);
        gload16(wth + boff + 2048 + t * 8, lds + 8320 + 2048 + t * 8);
        gload16(wtl + boff + t * 8, lds + 12416 + t * 8);
        gload16(wtl + boff + 2048 + t * 8, lds + 12416 + 2048 + t * 8);
        __syncthreads();  // staging complete (vmcnt+lgkm drained before barrier)
        sh8 ah[4], al[4], bh[4], bl[4];
#pragma unroll
        for (int j = 0; j < 4; ++j) {
          const int brd = (quad * 128 + wn * 64 + j * 16 + col) * 8;
          bh[j] = *reinterpret_cast<const sh8*>(lds + 8320 + brd);
          bl[j] = *reinterpret_cast<const sh8*>(lds + 12416 + brd);
        }
#pragma unroll
        for (int i = 0; i < 4; ++i) {
          const int ard = (quad * 130 + wm * 64 + i * 16 + col + kx) * 8;
          ah[i] = *reinterpret_cast<const sh8*>(lds + ard);
          al[i] = *reinterpret_cast<const sh8*>(lds + 4160 + ard);
        }
#pragma unroll
        for (int i = 0; i < 4; ++i)
#pragma unroll
          for (int j = 0; j < 4; ++j) {
            acc[i][j] = __builtin_amdgcn_mfma_f32_16x16x32_bf16(ah[i], bh[j], acc[i][j], 0, 0, 0);
            acc[i][j] = __builtin_amdgcn_mfma_f32_16x16x32_bf16(ah[i], bl[j], acc[i][j], 0, 0, 0);
            acc[i][j] = __builtin_amdgcn_mfma_f32_16x16x32_bf16(al[i], bh[j], acc[i][j], 0, 0, 0);
          }
      }
    }
  }
  const bool first = (nt < 4);
  float* outp = first ? lg : fxo;
  const float* bb = first ? bc : bfx;
  const int ocbase = (nt & 3) * 128 + wn * 64 + col;
#pragma unroll
  for (int j = 0; j < 4; ++j) {
    const int oc = ocbase + j * 16;
    const float bv = bb[oc];
#pragma unroll
    for (int i = 0; i < 4; ++i) {
#pragma unroll
      for (int r = 0; r < 4; ++r) {
        const int px = wm * 64 + i * 16 + quad * 4 + r;
        outp[((size_t)(y * W_ + px)) * INNER_ + oc] = acc[i][j][r] + bv;
      }
    }
  }
}

__device__ __forceinline__ void fma16(float (&acc)[4][4], const float4 a, const float4 b) {
  acc[0][0] = fmaf(a.x, b.x, acc[0][0]);
  acc[0][1] = fmaf(a.x, b.y, acc[0][1]);
  acc[0][2] = fmaf(a.x, b.z, acc[0][2]);
  acc[0][3] = fmaf(a.x, b.w, acc[0][3]);
  acc[1][0] = fmaf(a.y, b.x, acc[1][0]);
  acc[1][1] = fmaf(a.y, b.y, acc[1][1]);
  acc[1][2] = fmaf(a.y, b.z, acc[1][2]);
  acc[1][3] = fmaf(a.y, b.w, acc[1][3]);
  acc[2][0] = fmaf(a.z, b.x, acc[2][0]);
  acc[2][1] = fmaf(a.z, b.y, acc[2][1]);
  acc[2][2] = fmaf(a.z, b.z, acc[2][2]);
  acc[2][3] = fmaf(a.z, b.w, acc[2][3]);
  acc[3][0] = fmaf(a.w, b.x, acc[3][0]);
  acc[3][1] = fmaf(a.w, b.y, acc[3][1]);
  acc[3][2] = fmaf(a.w, b.z, acc[3][2]);
  acc[3][3] = fmaf(a.w, b.w, acc[3][3]);
}

// ONE batch. softmax (all 256 threads) -> packed hi/lo w in place, token+norm partials.
// grid 512 (h, 256-px chunk), block 256.
__global__ __launch_bounds__(256) void slice_kernel(float* __restrict__ lg,
                                                    const float* __restrict__ fxg,
                                                    float* __restrict__ tok,
                                                    float* __restrict__ nrm) {
  __shared__ __align__(16) float wl[64][68];
  __shared__ __align__(16) float fxl[64][68];
  __shared__ float red[8][64];
  unsigned int* lgp = reinterpret_cast<unsigned int*>(lg);

  const int t = threadIdx.x;
  const int sub = blockIdx.x & 63;
  const int h = blockIdx.x >> 6;
  const int nbase = sub * 256;
  const int tx = t & 15;
  const int ty = t >> 4;
  const int sn = t >> 2;   // softmax row
  const int sq = t & 3;    // softmax quarter (16 g each)
  const int gg2 = t & 63;  // norm column
  const int q2 = t >> 6;   // norm n-quarter

  float acc2[4][4] = {};
  float snrmp = 0.0f;

  for (int s = 0; s < 4; ++s) {
    const int n0 = nbase + s * 64;
    __syncthreads();
    {
      const int cg = t & 15;
      const int nr = t >> 4;
#pragma unroll
      for (int r = 0; r < 4; ++r) {
        const int nn = nr + r * 16;
        const size_t rowoff = ((size_t)(n0 + nn)) * INNER_ + h * DH_ + cg * 4;
        *reinterpret_cast<float4*>(&wl[nn][cg * 4]) =
            *reinterpret_cast<const float4*>(lg + rowoff);
        *reinterpret_cast<float4*>(&fxl[nn][cg * 4]) =
            *reinterpret_cast<const float4*>(fxg + rowoff);
      }
    }
    __syncthreads();
    // softmax over g per row, 4 threads/row
    float m = -3.4e38f;
#pragma unroll
    for (int jj = 0; jj < 16; ++jj) m = fmaxf(m, wl[sn][sq * 16 + jj]);
    red[sq][sn] = m;
    __syncthreads();
    m = fmaxf(fmaxf(red[0][sn], red[1][sn]), fmaxf(red[2][sn], red[3][sn]));
    float ss = 0.0f;
#pragma unroll
    for (int jj = 0; jj < 16; ++jj) {
      const float e = __expf(wl[sn][sq * 16 + jj] - m);
      wl[sn][sq * 16 + jj] = e;
      ss += e;
    }
    red[4 + sq][sn] = ss;
    __syncthreads();
    const float inv = 1.0f / (red[4][sn] + red[5][sn] + red[6][sn] + red[7][sn]);
#pragma unroll
    for (int jj = 0; jj < 16; ++jj) wl[sn][sq * 16 + jj] *= inv;
    __syncthreads();
    // packed write
    {
      const int gg = t & 15;
      const int nr = t >> 4;
#pragma unroll
      for (int r = 0; r < 4; ++r) {
        const int nn = nr + r * 16;
        uint4 pk;
        unsigned int* pp = reinterpret_cast<unsigned int*>(&pk);
#pragma unroll
        for (int j = 0; j < 4; ++j) {
          ushort hh, ll;
          split_bf16(wl[nn][gg * 4 + j], hh, ll);
          pp[j] = ((unsigned int)hh << 16) | (unsigned int)ll;
        }
        *reinterpret_cast<uint4*>(lgp + ((size_t)(n0 + nn)) * INNER_ + h * DH_ + gg * 4) = pk;
      }
    }
    // norm partial (distributed)
#pragma unroll
    for (int nn = 0; nn < 16; ++nn) snrmp += wl[q2 * 16 + nn][gg2];
    // token GEMM partial
#pragma unroll
    for (int kk = 0; kk < 64; ++kk) {
      const float4 a4 = *reinterpret_cast<const float4*>(&wl[kk][ty * 4]);
      const float4 b4 = *reinterpret_cast<const float4*>(&fxl[kk][tx * 4]);
      fma16(acc2, a4, b4);
    }
  }
  __syncthreads();
  red[q2][gg2] = snrmp;
  float* tokp = tok + (size_t)h * G_ * DH_;
#pragma unroll
  for (int i = 0; i < 4; ++i)
#pragma unroll
    for (int j = 0; j < 4; ++j)
      atomicAdd(tokp + (size_t)(ty * 4 + i) * DH_ + tx * 4 + j, acc2[i][j]);
  __syncthreads();
  if (t < 64) atomicAdd(nrm + (size_t)h * G_ + t,
                        red[0][t] + red[1][t] + red[2][t] + red[3][t]);
}

// ONE batch. Fused qkv+attn+outmat per head. grid 8, block 256.
__global__ __launch_bounds__(256) void head_kernel(const float* __restrict__ tok,
                                                   const float* __restrict__ nrm,
                                                   const float* __restrict__ mqk,
                                                   const float* __restrict__ Wv,
                                                   const float* __restrict__ Wo,
                                                   ushort* __restrict__ mht,
                                                   ushort* __restrict__ mlt) {
  __shared__ float ST[64 * 65];
  __shared__ float YL[64 * 64];
  __shared__ float VL[64 * 64];
  __shared__ float red[8][64];
  const int t = threadIdx.x;
  const int h = blockIdx.x;

  for (int e = t; e < 4096; e += 256) {
    const int g = e >> 6, c = e & 63;
    ST[g * 65 + c] = tok[(size_t)h * 4096 + e] / (nrm[h * 64 + g] + 1e-5f);
  }
  __syncthreads();
  for (int e = t; e < 4096; e += 256) {
    const int k = e >> 6, c = e & 63;
    float sy = 0.f, sv = 0.f;
    const float* mrow = mqk + c * 64;
    const float* wrow = Wv + c * 64;
#pragma unroll
    for (int c2 = 0; c2 < 64; ++c2) {
      const float st2 = ST[k * 65 + c2];
      sy = fmaf(mrow[c2], st2, sy);
      sv = fmaf(wrow[c2], st2, sv);
    }
    YL[k * 64 + c] = sy;
    VL[k * 64 + c] = sv;
  }
  __syncthreads();
  const int g = t & 63, kp = t >> 6;
  float z[16];
#pragma unroll
  for (int j = 0; j < 16; ++j) z[j] = 0.f;
  for (int c = 0; c < 64; ++c) {
    const float sg = ST[g * 65 + c];
#pragma unroll
    for (int j = 0; j < 16; ++j) z[j] = fmaf(sg, YL[(kp * 16 + j) * 64 + c], z[j]);
  }
  float m = z[0];
#pragma unroll
  for (int j = 1; j < 16; ++j) m = fmaxf(m, z[j]);
  red[kp][g] = m;
  __syncthreads();
  m = fmaxf(fmaxf(red[0][g], red[1][g]), fmaxf(red[2][g], red[3][g]));
  float ssum = 0.f;
#pragma unroll
  for (int j = 0; j < 16; ++j) {
    z[j] = __expf(z[j] - m);
    ssum += z[j];
  }
  red[4 + kp][g] = ssum;
  __syncthreads();
  ssum = red[4][g] + red[5][g] + red[6][g] + red[7][g];
  const float inv = 1.f / ssum;
#pragma unroll
  for (int j = 0; j < 16; ++j) ST[(kp * 16 + j) * 65 + g] = z[j] * inv;
  __syncthreads();
  for (int e = t; e < 4096; e += 256) {
    const int gg = e >> 6, d = e & 63;
    float s = 0.f;
#pragma unroll
    for (int k = 0; k < 64; ++k) s = fmaf(ST[k * 65 + gg], VL[k * 64 + d], s);
    YL[gg * 64 + d] = s;
  }
  __syncthreads();
  for (int e = t; e < 8192; e += 256) {
    const int o = e & 127, gg = e >> 7;
    float s = 0.f;
    const float* wrow = Wo + (size_t)o * INNER_ + h * 64;
#pragma unroll
    for (int d = 0; d < 64; ++d) s = fmaf(YL[gg * 64 + d], wrow[d], s);
    ushort hh, ll;
    split_bf16(s, hh, ll);
    const int hg = h * 64 + gg;
    const int kg2 = hg >> 3, kr = hg & 7;
    mht[((size_t)kg2 * 128 + o) * 8 + kr] = hh;
    mlt[((size_t)kg2 * 128 + o) * 8 + kr] = ll;
  }
}

// ONE batch. out[n][o] = sum_k w[n][k]*Mcat[k][o] + bo[o]; bf16x3 MFMA. grid 256.
__global__ __launch_bounds__(256) void fused_out_kernel(
    const unsigned int* __restrict__ wp,
    const ushort* __restrict__ mht,
    const ushort* __restrict__ mlt,
    const float* __restrict__ bo,
    float* __restrict__ out) {
  __shared__ __align__(16) ushort lds[24576];
  const int t = threadIdx.x;
  const int lane = t & 63;
  const int wid = t >> 6;
  const int wm = wid & 1, wn = wid >> 1;
  const int col = lane & 15, quad = lane >> 4;
  const int n0 = blockIdx.x * 64;

  vf4 acc[2][4];
#pragma unroll
  for (int m = 0; m < 2; ++m)
#pragma unroll
    for (int n = 0; n < 4; ++n) acc[m][n] = vf4{0.f, 0.f, 0.f, 0.f};

  for (int kc = 0; kc < 8; ++kc) {
    __syncthreads();
#pragma unroll
    for (int r = 0; r < 2; ++r) {
      const int row = r * 256 + t;
      const int pix = row >> 3, kg2 = row & 7;
      const unsigned int* gp = wp + (size_t)(n0 + pix) * INNER_ + kc * 64 + kg2 * 8;
      const uint4 p0 = *reinterpret_cast<const uint4*>(gp);
      const uint4 p1 = *reinterpret_cast<const uint4*>(gp + 4);
      unsigned int u[8] = {p0.x, p0.y, p0.z, p0.w, p1.x, p1.y, p1.z, p1.w};
      sh8 hv, lv;
#pragma unroll
      for (int j = 0; j < 8; ++j) {
        hv[j] = (short)(u[j] >> 16);
        lv[j] = (short)(u[j] & 0xffff);
      }
      const int drow = pix * 8 + (kg2 ^ (pix & 7));
      *reinterpret_cast<sh8*>(lds + drow * 8) = hv;
      *reinterpret_cast<sh8*>(lds + 4096 + drow * 8) = lv;
    }
#pragma unroll
    for (int r = 0; r < 4; ++r) {
      gload16(mht + (size_t)kc * 8192 + ((size_t)r * 256 + t) * 8, lds + 8192 + r * 2048 + t * 8);
      gload16(mlt + (size_t)kc * 8192 + ((size_t)r * 256 + t) * 8, lds + 16384 + r * 2048 + t * 8);
    }
    __syncthreads();
#pragma unroll
    for (int kk = 0; kk < 2; ++kk) {
      const int kg2 = kk * 4 + quad;
      sh8 ah[2], al[2], bh[4], bl[4];
#pragma unroll
      for (int m = 0; m < 2; ++m) {
        const int pix = wm * 32 + m * 16 + col;
        const int drow = pix * 8 + (kg2 ^ (pix & 7));
        ah[m] = *reinterpret_cast<const sh8*>(lds + drow * 8);
        al[m] = *reinterpret_cast<const sh8*>(lds + 4096 + drow * 8);
      }
#pragma unroll
      for (int n = 0; n < 4; ++n) {
        const int o = wn * 64 + n * 16 + col;
        bh[n] = *reinterpret_cast<const sh8*>(lds + 8192 + ((size_t)kg2 * 128 + o) * 8);
        bl[n] = *reinterpret_cast<const sh8*>(lds + 16384 + ((size_t)kg2 * 128 + o) * 8);
      }
#pragma unroll
      for (int m = 0; m < 2; ++m)
#pragma unroll
        for (int n = 0; n < 4; ++n) {
          acc[m][n] = __builtin_amdgcn_mfma_f32_16x16x32_bf16(ah[m], bh[n], acc[m][n], 0, 0, 0);
          acc[m][n] = __builtin_amdgcn_mfma_f32_16x16x32_bf16(ah[m], bl[n], acc[m][n], 0, 0, 0);
          acc[m][n] = __builtin_amdgcn_mfma_f32_16x16x32_bf16(al[m], bh[n], acc[m][n], 0, 0, 0);
        }
    }
  }
#pragma unroll
  for (int n = 0; n < 4; ++n) {
    const int o = wn * 64 + n * 16 + col;
    const float bv = bo[o];
#pragma unroll
    for (int m = 0; m < 2; ++m) {
#pragma unroll
      for (int r = 0; r < 4; ++r) {
        const int pix = wm * 32 + m * 16 + quad * 4 + r;
        out[(size_t)(n0 + pix) * DIM_ + o] = acc[m][n][r] + bv;
      }
    }
  }
}

extern "C" void kernel_launch(void* const* d_in, const int* in_sizes, int n_in,
                              void* d_out, int out_size, void* d_ws, size_t ws_size,
                              hipStream_t stream) {
  const float* x    = (const float*)d_in[0];
  const float* temp = (const float*)d_in[1];
  const float* Wx   = (const float*)d_in[2];
  const float* bx   = (const float*)d_in[3];
  const float* Wfx  = (const float*)d_in[4];
  const float* bfx  = (const float*)d_in[5];
  const float* Ws   = (const float*)d_in[6];
  const float* bs   = (const float*)d_in[7];
  const float* Wq   = (const float*)d_in[8];
  const float* Wk   = (const float*)d_in[9];
  const float* Wv   = (const float*)d_in[10];
  const float* Wo   = (const float*)d_in[11];
  const float* bo   = (const float*)d_in[12];
  float* out = (float*)d_out;

  char* p = (char*)d_ws;
  ushort* WTH = (ushort*)p; p += (size_t)WT_PLANE * 2;
  ushort* WTL = (ushort*)p; p += (size_t)WT_PLANE * 2;
  ushort* XPTH = (ushort*)p; p += (size_t)XPT_PLANE * 2;
  ushort* XPTL = (ushort*)p; p += (size_t)XPT_PLANE * 2;
  float* LG  = (float*)p; p += (size_t)N_ * INNER_ * 4;   // logits -> packed w
  float* FXO = (float*)p; p += (size_t)N_ * INNER_ * 4;   // fx_mid
  float* TOK = (float*)p; p += (size_t)B_ * HEADS_ * G_ * DH_ * 4;
  float* NRM = (float*)p; p += (size_t)B_ * HEADS_ * G_ * 4;
  float* MQK = (float*)p; p += (size_t)DH_ * DH_ * 4;
  float* BC  = (float*)p; p += (size_t)INNER_ * 4;
  ushort* MHT = (ushort*)p; p += (size_t)INNER_ * DIM_ * 2;
  ushort* MLT = (ushort*)p; p += (size_t)INNER_ * DIM_ * 2;

  hipMemsetAsync(TOK, 0, (size_t)(B_ * HEADS_ * G_ * DH_ + B_ * HEADS_ * G_) * sizeof(float), stream);
  wfx_kernel<<<2304, 256, 0, stream>>>(Wfx, WTH, WTL);
  wcomp_kernel<<<dim3(9, 8), 256, 0, stream>>>(Wx, Ws, bx, bs, temp, WTH, WTL, BC);
  mqk_kernel<<<16, 256, 0, stream>>>(Wq, Wk, MQK);

  for (int b = 0; b < B_; ++b) {
    const float* xb = x + (size_t)b * N_ * DIM_;
    float* outb = out + (size_t)b * N_ * DIM_;
    float* tokb = TOK + (size_t)b * HEADS_ * G_ * DH_;
    float* nrmb = NRM + (size_t)b * HEADS_ * G_;

    pad_tile_kernel<<<8450, 256, 0, stream>>>(xb, XPTH, XPTL);
    conv_mfma_kernel<<<dim3(128, 8), 256, 0, stream>>>(XPTH, XPTL, WTH, WTL, BC, bfx, LG, FXO);
    slice_kernel<<<512, 256, 0, stream>>>(LG, FXO, tokb, nrmb);
    head_kernel<<<8, 256, 0, stream>>>(tokb, nrmb, MQK, Wv, Wo, MHT, MLT);
    fused_out_kernel<<<256, 256, 0, stream>>>((const unsigned int*)LG, MHT, MLT, bo, outb);
  }
}

// Round 8
// 972.207 us; speedup vs baseline: 3.1236x; 1.0542x over previous
//
#include <hip/hip_runtime.h>
#include <hip/hip_bf16.h>
#include <math.h>

#define B_ 4
#define H_ 128
#define W_ 128
#define DIM_ 128
#define HEADS_ 8
#define DH_ 64
#define G_ 64
#define INNER_ 512
#define N_ 16384

typedef __attribute__((ext_vector_type(8))) short sh8;
typedef __attribute__((ext_vector_type(4))) float vf4;

// XPT tiled input layout (per plane): [row 0..129][c0 0..3][tile 0..519][8]
//   tile = kg*130 + px  (kg = channel-group of 8 within 32-chunk, px = padded col)
// slab per (row,c0) = 520*8 = 4160 shorts.  plane = 130*4*4160 = 2163200 shorts.
#define XPT_SLAB 4160
#define XPT_PLANE 2163200
// WT tiled weight layout (per plane): [tap 0..8][nt 0..7][c0 0..3][tile 0..511][8]
//   tile = kg*128 + oc(0..127), oc global = nt*128+oc.
#define WT_PLANE 1179648

__device__ __forceinline__ void gload16(const void* g, void* l) {
  __builtin_amdgcn_global_load_lds((const __attribute__((address_space(1))) void*)g,
                                   (__attribute__((address_space(3))) void*)l, 16, 0, 0);
}

__device__ __forceinline__ void split_bf16(float v, ushort& h, ushort& l) {
  __hip_bfloat16 hb = __float2bfloat16(v);
  float hf = __bfloat162float(hb);
  __hip_bfloat16 lb = __float2bfloat16(v - hf);
  h = *reinterpret_cast<ushort*>(&hb);
  l = *reinterpret_cast<ushort*>(&lb);
}

// ---- prep: pad+split one batch of x directly into XPT tiled hi/lo layout ----
__global__ __launch_bounds__(256) void pad_tile_kernel(const float* __restrict__ x,
                                                       ushort* __restrict__ xpth,
                                                       ushort* __restrict__ xptl) {
  const int idx = blockIdx.x * 256 + threadIdx.x;  // 2163200 exactly (8450 blocks)
  const int row = idx / (4 * XPT_SLAB);
  const int rem = idx % (4 * XPT_SLAB);
  const int c0i = rem / XPT_SLAB;
  const int t2 = rem % XPT_SLAB;
  const int tile = t2 >> 3, j = t2 & 7;
  const int kg = tile / 130, px = tile % 130;
  const int c = c0i * 32 + kg * 8 + j;
  float v = 0.0f;
  if (row >= 1 && row <= H_ && px >= 1 && px <= W_)
    v = x[((size_t)(row - 1) * W_ + (px - 1)) * DIM_ + c];
  ushort hh, ll;
  split_bf16(v, hh, ll);
  xpth[idx] = hh;
  xptl[idx] = ll;
}

// ---- prep: fx-branch weights into WT tiled layout (nt 4..7) ----
__global__ __launch_bounds__(256) void wfx_kernel(const float* __restrict__ Wfx,
                                                  ushort* __restrict__ wth,
                                                  ushort* __restrict__ wtl) {
  int idx = blockIdx.x * 256 + threadIdx.x;
  if (idx >= 9 * 512 * DIM_) return;
  const int c = idx & 127;
  const int ocf = (idx >> 7) & 511;
  const int tap = idx >> 16;
  float v = Wfx[((size_t)ocf * DIM_ + c) * 9 + tap];
  ushort hh, ll;
  split_bf16(v, hh, ll);
  const int nt = 4 + (ocf >> 7), oci = ocf & 127;
  const int c0i = c >> 5, kg = (c >> 3) & 3, j = c & 7;
  const size_t o = (((size_t)tap * 8 + nt) * 4 + c0i) * 4096 + ((size_t)kg * 128 + oci) * 8 + j;
  wth[o] = hh;
  wtl[o] = ll;
}

// ---- prep: composed x-branch weights (Ws/temp folded), WT tiled (nt 0..3) + bias bc ----
__global__ __launch_bounds__(256) void wcomp_kernel(const float* __restrict__ Wx,
                                                    const float* __restrict__ Ws,
                                                    const float* __restrict__ bx,
                                                    const float* __restrict__ bs,
                                                    const float* __restrict__ temperature,
                                                    ushort* __restrict__ wth,
                                                    ushort* __restrict__ wtl,
                                                    float* __restrict__ bc) {
  __shared__ float WxL[64][128];
  __shared__ float WsL[64][64];
  const int t = threadIdx.x;
  const int tap = blockIdx.x, h = blockIdx.y;
  for (int e = t; e < 8192; e += 256) {
    const int c2 = e >> 7, c = e & 127;
    WxL[c2][c] = Wx[((size_t)(h * 64 + c2) * DIM_ + c) * 9 + tap];
  }
  for (int e = t; e < 4096; e += 256) WsL[e >> 6][e & 63] = Ws[e];
  float tmp = fminf(fmaxf(temperature[h], 0.1f), 5.0f);
  const float invt = 1.0f / tmp;
  __syncthreads();
  for (int e = t; e < 8192; e += 256) {
    const int gg = e >> 7, c = e & 127;
    float s = 0.f;
#pragma unroll
    for (int c2 = 0; c2 < 64; ++c2) s = fmaf(WsL[gg][c2], WxL[c2][c], s);
    s *= invt;
    ushort hh, ll;
    split_bf16(s, hh, ll);
    const int ocp = h * 64 + gg;
    const int nt = ocp >> 7, oci = ocp & 127;
    const int c0i = c >> 5, kg = (c >> 3) & 3, j = c & 7;
    const size_t o = (((size_t)tap * 8 + nt) * 4 + c0i) * 4096 + ((size_t)kg * 128 + oci) * 8 + j;
    wth[o] = hh;
    wtl[o] = ll;
  }
  if (tap == 0 && t < 64) {
    float s = 0.f;
#pragma unroll
    for (int c2 = 0; c2 < 64; ++c2) s = fmaf(Ws[t * 64 + c2], bx[h * 64 + c2], s);
    bc[h * 64 + t] = (s + bs[t]) * invt;
  }
}

// ---- prep: Mqk[c][c'] = scale * sum_d Wq[d][c]*Wk[d][c'] ----
__global__ __launch_bounds__(256) void mqk_kernel(const float* __restrict__ Wq,
                                                  const float* __restrict__ Wk,
                                                  float* __restrict__ mqk) {
  const int idx = blockIdx.x * 256 + threadIdx.x;  // 4096
  const int c = idx >> 6, c2 = idx & 63;
  float s = 0.f;
#pragma unroll
  for (int d = 0; d < 64; ++d) s = fmaf(Wq[d * 64 + c], Wk[d * 64 + c2], s);
  mqk[idx] = s * 0.125f;
}

// ---- bf16x3 MFMA conv, contiguous staging + A-reuse across kx. one batch.
// grid (8 nt, 128 rows) — nt fastest so consecutive block ids (round-robin across
// XCDs) pin each nt's 576 KB weight slice to one XCD's L2. nt 0..3 -> logits,
// 4..7 -> fx_mid. block 256 (4 waves, 2x2).
__global__ __launch_bounds__(256) void conv_mfma_kernel(
    const ushort* __restrict__ xpth, const ushort* __restrict__ xptl,
    const ushort* __restrict__ wth, const ushort* __restrict__ wtl,
    const float* __restrict__ bc, const float* __restrict__ bfx,
    float* __restrict__ lg, float* __restrict__ fxo) {
  // shorts: Ah@0 (4160), Al@4160, Bh@8320 (4096), Bl@12416. total 33024 B.
  __shared__ __align__(16) ushort lds[16512];
  const int t = threadIdx.x;
  const int lane = t & 63;
  const int wid = t >> 6;
  const int wm = wid & 1, wn = wid >> 1;
  const int nt = blockIdx.x;
  const int y = blockIdx.y;
  const int col = lane & 15, quad = lane >> 4;

  vf4 acc[4][4];
#pragma unroll
  for (int i = 0; i < 4; ++i)
#pragma unroll
    for (int j = 0; j < 4; ++j) acc[i][j] = vf4{0.f, 0.f, 0.f, 0.f};

  for (int ky = 0; ky < 3; ++ky) {
    for (int c0i = 0; c0i < 4; ++c0i) {
      const size_t aoff = ((size_t)(y + ky) * 4 + c0i) * XPT_SLAB;
      __syncthreads();  // prior phase's LDS reads done
      // A stage: 4160 shorts/plane; two full-block gloads + predicated scalar tail
      gload16(xpth + aoff + t * 8, lds + t * 8);
      gload16(xpth + aoff + 2048 + t * 8, lds + 2048 + t * 8);
      gload16(xptl + aoff + t * 8, lds + 4160 + t * 8);
      gload16(xptl + aoff + 2048 + t * 8, lds + 4160 + 2048 + t * 8);
      if (t < 8) {
        *reinterpret_cast<sh8*>(lds + 4096 + t * 8) =
            *reinterpret_cast<const sh8*>(xpth + aoff + 4096 + t * 8);
        *reinterpret_cast<sh8*>(lds + 4160 + 4096 + t * 8) =
            *reinterpret_cast<const sh8*>(xptl + aoff + 4096 + t * 8);
      }
      for (int kx = 0; kx < 3; ++kx) {
        const int tap = ky * 3 + kx;
        const size_t boff = (((size_t)tap * 8 + nt) * 4 + c0i) * 4096;
        if (kx > 0) __syncthreads();  // prior kx's B reads done
        gload16(wth + boff + t * 8, lds + 8320 + t * 8);
        gload16(wth + boff + 2048 + t * 8, lds + 8320 + 2048 + t * 8);
        gload16(wtl + boff + t * 8, lds + 12416 + t * 8);
        gload16(wtl + boff + 2048 + t * 8, lds + 12416 + 2048 + t * 8);
        __syncthreads();  // staging complete (vmcnt+lgkm drained before barrier)
        sh8 ah[4], al[4], bh[4], bl[4];
#pragma unroll
        for (int j = 0; j < 4; ++j) {
          const int brd = (quad * 128 + wn * 64 + j * 16 + col) * 8;
          bh[j] = *reinterpret_cast<const sh8*>(lds + 8320 + brd);
          bl[j] = *reinterpret_cast<const sh8*>(lds + 12416 + brd);
        }
#pragma unroll
        for (int i = 0; i < 4; ++i) {
          const int ard = (quad * 130 + wm * 64 + i * 16 + col + kx) * 8;
          ah[i] = *reinterpret_cast<const sh8*>(lds + ard);
          al[i] = *reinterpret_cast<const sh8*>(lds + 4160 + ard);
        }
#pragma unroll
        for (int i = 0; i < 4; ++i)
#pragma unroll
          for (int j = 0; j < 4; ++j) {
            acc[i][j] = __builtin_amdgcn_mfma_f32_16x16x32_bf16(ah[i], bh[j], acc[i][j], 0, 0, 0);
            acc[i][j] = __builtin_amdgcn_mfma_f32_16x16x32_bf16(ah[i], bl[j], acc[i][j], 0, 0, 0);
            acc[i][j] = __builtin_amdgcn_mfma_f32_16x16x32_bf16(al[i], bh[j], acc[i][j], 0, 0, 0);
          }
      }
    }
  }
  const bool first = (nt < 4);
  float* outp = first ? lg : fxo;
  const float* bb = first ? bc : bfx;
  const int ocbase = (nt & 3) * 128 + wn * 64 + col;
#pragma unroll
  for (int j = 0; j < 4; ++j) {
    const int oc = ocbase + j * 16;
    const float bv = bb[oc];
#pragma unroll
    for (int i = 0; i < 4; ++i) {
#pragma unroll
      for (int r = 0; r < 4; ++r) {
        const int px = wm * 64 + i * 16 + quad * 4 + r;
        outp[((size_t)(y * W_ + px)) * INNER_ + oc] = acc[i][j][r] + bv;
      }
    }
  }
}

__device__ __forceinline__ void fma16(float (&acc)[4][4], const float4 a, const float4 b) {
  acc[0][0] = fmaf(a.x, b.x, acc[0][0]);
  acc[0][1] = fmaf(a.x, b.y, acc[0][1]);
  acc[0][2] = fmaf(a.x, b.z, acc[0][2]);
  acc[0][3] = fmaf(a.x, b.w, acc[0][3]);
  acc[1][0] = fmaf(a.y, b.x, acc[1][0]);
  acc[1][1] = fmaf(a.y, b.y, acc[1][1]);
  acc[1][2] = fmaf(a.y, b.z, acc[1][2]);
  acc[1][3] = fmaf(a.y, b.w, acc[1][3]);
  acc[2][0] = fmaf(a.z, b.x, acc[2][0]);
  acc[2][1] = fmaf(a.z, b.y, acc[2][1]);
  acc[2][2] = fmaf(a.z, b.z, acc[2][2]);
  acc[2][3] = fmaf(a.z, b.w, acc[2][3]);
  acc[3][0] = fmaf(a.w, b.x, acc[3][0]);
  acc[3][1] = fmaf(a.w, b.y, acc[3][1]);
  acc[3][2] = fmaf(a.w, b.z, acc[3][2]);
  acc[3][3] = fmaf(a.w, b.w, acc[3][3]);
}

// ONE batch. softmax (all 256 threads) -> packed hi/lo w in place, NON-ATOMIC
// per-block token/norm partials. grid 512 (h, 256-px chunk), block 256.
__global__ __launch_bounds__(256) void slice_kernel(float* __restrict__ lg,
                                                    const float* __restrict__ fxg,
                                                    float* __restrict__ tpart,  // [512][4096]
                                                    float* __restrict__ npart) { // [512][64]
  __shared__ __align__(16) float wl[64][68];
  __shared__ __align__(16) float fxl[64][68];
  __shared__ float red[8][64];
  unsigned int* lgp = reinterpret_cast<unsigned int*>(lg);

  const int t = threadIdx.x;
  const int sub = blockIdx.x & 63;
  const int h = blockIdx.x >> 6;
  const int nbase = sub * 256;
  const int tx = t & 15;
  const int ty = t >> 4;
  const int sn = t >> 2;   // softmax row
  const int sq = t & 3;    // softmax quarter (16 g each)
  const int gg2 = t & 63;  // norm column
  const int q2 = t >> 6;   // norm n-quarter

  float acc2[4][4] = {};
  float snrmp = 0.0f;

  for (int s = 0; s < 4; ++s) {
    const int n0 = nbase + s * 64;
    __syncthreads();
    {
      const int cg = t & 15;
      const int nr = t >> 4;
#pragma unroll
      for (int r = 0; r < 4; ++r) {
        const int nn = nr + r * 16;
        const size_t rowoff = ((size_t)(n0 + nn)) * INNER_ + h * DH_ + cg * 4;
        *reinterpret_cast<float4*>(&wl[nn][cg * 4]) =
            *reinterpret_cast<const float4*>(lg + rowoff);
        *reinterpret_cast<float4*>(&fxl[nn][cg * 4]) =
            *reinterpret_cast<const float4*>(fxg + rowoff);
      }
    }
    __syncthreads();
    // softmax over g per row, 4 threads/row
    float m = -3.4e38f;
#pragma unroll
    for (int jj = 0; jj < 16; ++jj) m = fmaxf(m, wl[sn][sq * 16 + jj]);
    red[sq][sn] = m;
    __syncthreads();
    m = fmaxf(fmaxf(red[0][sn], red[1][sn]), fmaxf(red[2][sn], red[3][sn]));
    float ss = 0.0f;
#pragma unroll
    for (int jj = 0; jj < 16; ++jj) {
      const float e = __expf(wl[sn][sq * 16 + jj] - m);
      wl[sn][sq * 16 + jj] = e;
      ss += e;
    }
    red[4 + sq][sn] = ss;
    __syncthreads();
    const float inv = 1.0f / (red[4][sn] + red[5][sn] + red[6][sn] + red[7][sn]);
#pragma unroll
    for (int jj = 0; jj < 16; ++jj) wl[sn][sq * 16 + jj] *= inv;
    __syncthreads();
    // packed write
    {
      const int gg = t & 15;
      const int nr = t >> 4;
#pragma unroll
      for (int r = 0; r < 4; ++r) {
        const int nn = nr + r * 16;
        uint4 pk;
        unsigned int* pp = reinterpret_cast<unsigned int*>(&pk);
#pragma unroll
        for (int j = 0; j < 4; ++j) {
          ushort hh, ll;
          split_bf16(wl[nn][gg * 4 + j], hh, ll);
          pp[j] = ((unsigned int)hh << 16) | (unsigned int)ll;
        }
        *reinterpret_cast<uint4*>(lgp + ((size_t)(n0 + nn)) * INNER_ + h * DH_ + gg * 4) = pk;
      }
    }
    // norm partial (distributed)
#pragma unroll
    for (int nn = 0; nn < 16; ++nn) snrmp += wl[q2 * 16 + nn][gg2];
    // token GEMM partial
#pragma unroll
    for (int kk = 0; kk < 64; ++kk) {
      const float4 a4 = *reinterpret_cast<const float4*>(&wl[kk][ty * 4]);
      const float4 b4 = *reinterpret_cast<const float4*>(&fxl[kk][tx * 4]);
      fma16(acc2, a4, b4);
    }
  }
  __syncthreads();
  red[q2][gg2] = snrmp;
  // flush partials (non-atomic, coalesced float4)
  float* tp = tpart + (size_t)blockIdx.x * 4096;
#pragma unroll
  for (int i = 0; i < 4; ++i) {
    float4 v;
    v.x = acc2[i][0];
    v.y = acc2[i][1];
    v.z = acc2[i][2];
    v.w = acc2[i][3];
    *reinterpret_cast<float4*>(tp + (ty * 4 + i) * 64 + tx * 4) = v;
  }
  __syncthreads();
  if (t < 64)
    npart[(size_t)blockIdx.x * 64 + t] = red[0][t] + red[1][t] + red[2][t] + red[3][t];
}

// ONE batch. Sum 64 chunk partials -> tok [8][4096], nrm [8][64]. grid 129, block 256.
__global__ __launch_bounds__(256) void reduce_kernel(const float* __restrict__ tpart,
                                                     const float* __restrict__ npart,
                                                     float* __restrict__ tok,
                                                     float* __restrict__ nrm) {
  if (blockIdx.x < 128) {
    const int idx = blockIdx.x * 256 + threadIdx.x;  // 32768
    const int h = idx >> 12, e = idx & 4095;
    float s = 0.f;
    for (int cb = 0; cb < 64; ++cb)
      s += tpart[(((size_t)(h * 64 + cb)) << 12) + e];
    tok[idx] = s;
  } else {
    for (int o = threadIdx.x; o < 512; o += 256) {
      const int h = o >> 6, g = o & 63;
      float s = 0.f;
      for (int cb = 0; cb < 64; ++cb) s += npart[(size_t)(h * 64 + cb) * 64 + g];
      nrm[o] = s;
    }
  }
}

// ONE batch. Fused qkv+attn+outmat per head. grid 8, block 256.
__global__ __launch_bounds__(256) void head_kernel(const float* __restrict__ tok,
                                                   const float* __restrict__ nrm,
                                                   const float* __restrict__ mqk,
                                                   const float* __restrict__ Wv,
                                                   const float* __restrict__ Wo,
                                                   ushort* __restrict__ mht,
                                                   ushort* __restrict__ mlt) {
  __shared__ float ST[64 * 65];
  __shared__ float YL[64 * 64];
  __shared__ float VL[64 * 64];
  __shared__ float red[8][64];
  const int t = threadIdx.x;
  const int h = blockIdx.x;

  for (int e = t; e < 4096; e += 256) {
    const int g = e >> 6, c = e & 63;
    ST[g * 65 + c] = tok[(size_t)h * 4096 + e] / (nrm[h * 64 + g] + 1e-5f);
  }
  __syncthreads();
  for (int e = t; e < 4096; e += 256) {
    const int k = e >> 6, c = e & 63;
    float sy = 0.f, sv = 0.f;
    const float* mrow = mqk + c * 64;
    const float* wrow = Wv + c * 64;
#pragma unroll
    for (int c2 = 0; c2 < 64; ++c2) {
      const float st2 = ST[k * 65 + c2];
      sy = fmaf(mrow[c2], st2, sy);
      sv = fmaf(wrow[c2], st2, sv);
    }
    YL[k * 64 + c] = sy;
    VL[k * 64 + c] = sv;
  }
  __syncthreads();
  const int g = t & 63, kp = t >> 6;
  float z[16];
#pragma unroll
  for (int j = 0; j < 16; ++j) z[j] = 0.f;
  for (int c = 0; c < 64; ++c) {
    const float sg = ST[g * 65 + c];
#pragma unroll
    for (int j = 0; j < 16; ++j) z[j] = fmaf(sg, YL[(kp * 16 + j) * 64 + c], z[j]);
  }
  float m = z[0];
#pragma unroll
  for (int j = 1; j < 16; ++j) m = fmaxf(m, z[j]);
  red[kp][g] = m;
  __syncthreads();
  m = fmaxf(fmaxf(red[0][g], red[1][g]), fmaxf(red[2][g], red[3][g]));
  float ssum = 0.f;
#pragma unroll
  for (int j = 0; j < 16; ++j) {
    z[j] = __expf(z[j] - m);
    ssum += z[j];
  }
  red[4 + kp][g] = ssum;
  __syncthreads();
  ssum = red[4][g] + red[5][g] + red[6][g] + red[7][g];
  const float inv = 1.f / ssum;
#pragma unroll
  for (int j = 0; j < 16; ++j) ST[(kp * 16 + j) * 65 + g] = z[j] * inv;
  __syncthreads();
  for (int e = t; e < 4096; e += 256) {
    const int gg = e >> 6, d = e & 63;
    float s = 0.f;
#pragma unroll
    for (int k = 0; k < 64; ++k) s = fmaf(ST[k * 65 + gg], VL[k * 64 + d], s);
    YL[gg * 64 + d] = s;
  }
  __syncthreads();
  for (int e = t; e < 8192; e += 256) {
    const int o = e & 127, gg = e >> 7;
    float s = 0.f;
    const float* wrow = Wo + (size_t)o * INNER_ + h * 64;
#pragma unroll
    for (int d = 0; d < 64; ++d) s = fmaf(YL[gg * 64 + d], wrow[d], s);
    ushort hh, ll;
    split_bf16(s, hh, ll);
    const int hg = h * 64 + gg;
    const int kg2 = hg >> 3, kr = hg & 7;
    mht[((size_t)kg2 * 128 + o) * 8 + kr] = hh;
    mlt[((size_t)kg2 * 128 + o) * 8 + kr] = ll;
  }
}

// ONE batch. out[n][o] = sum_k w[n][k]*Mcat[k][o] + bo[o]; bf16x3 MFMA. grid 256.
__global__ __launch_bounds__(256) void fused_out_kernel(
    const unsigned int* __restrict__ wp,
    const ushort* __restrict__ mht,
    const ushort* __restrict__ mlt,
    const float* __restrict__ bo,
    float* __restrict__ out) {
  __shared__ __align__(16) ushort lds[24576];
  const int t = threadIdx.x;
  const int lane = t & 63;
  const int wid = t >> 6;
  const int wm = wid & 1, wn = wid >> 1;
  const int col = lane & 15, quad = lane >> 4;
  const int n0 = blockIdx.x * 64;

  vf4 acc[2][4];
#pragma unroll
  for (int m = 0; m < 2; ++m)
#pragma unroll
    for (int n = 0; n < 4; ++n) acc[m][n] = vf4{0.f, 0.f, 0.f, 0.f};

  for (int kc = 0; kc < 8; ++kc) {
    __syncthreads();
#pragma unroll
    for (int r = 0; r < 2; ++r) {
      const int row = r * 256 + t;
      const int pix = row >> 3, kg2 = row & 7;
      const unsigned int* gp = wp + (size_t)(n0 + pix) * INNER_ + kc * 64 + kg2 * 8;
      const uint4 p0 = *reinterpret_cast<const uint4*>(gp);
      const uint4 p1 = *reinterpret_cast<const uint4*>(gp + 4);
      unsigned int u[8] = {p0.x, p0.y, p0.z, p0.w, p1.x, p1.y, p1.z, p1.w};
      sh8 hv, lv;
#pragma unroll
      for (int j = 0; j < 8; ++j) {
        hv[j] = (short)(u[j] >> 16);
        lv[j] = (short)(u[j] & 0xffff);
      }
      const int drow = pix * 8 + (kg2 ^ (pix & 7));
      *reinterpret_cast<sh8*>(lds + drow * 8) = hv;
      *reinterpret_cast<sh8*>(lds + 4096 + drow * 8) = lv;
    }
#pragma unroll
    for (int r = 0; r < 4; ++r) {
      gload16(mht + (size_t)kc * 8192 + ((size_t)r * 256 + t) * 8, lds + 8192 + r * 2048 + t * 8);
      gload16(mlt + (size_t)kc * 8192 + ((size_t)r * 256 + t) * 8, lds + 16384 + r * 2048 + t * 8);
    }
    __syncthreads();
#pragma unroll
    for (int kk = 0; kk < 2; ++kk) {
      const int kg2 = kk * 4 + quad;
      sh8 ah[2], al[2], bh[4], bl[4];
#pragma unroll
      for (int m = 0; m < 2; ++m) {
        const int pix = wm * 32 + m * 16 + col;
        const int drow = pix * 8 + (kg2 ^ (pix & 7));
        ah[m] = *reinterpret_cast<const sh8*>(lds + drow * 8);
        al[m] = *reinterpret_cast<const sh8*>(lds + 4096 + drow * 8);
      }
#pragma unroll
      for (int n = 0; n < 4; ++n) {
        const int o = wn * 64 + n * 16 + col;
        bh[n] = *reinterpret_cast<const sh8*>(lds + 8192 + ((size_t)kg2 * 128 + o) * 8);
        bl[n] = *reinterpret_cast<const sh8*>(lds + 16384 + ((size_t)kg2 * 128 + o) * 8);
      }
#pragma unroll
      for (int m = 0; m < 2; ++m)
#pragma unroll
        for (int n = 0; n < 4; ++n) {
          acc[m][n] = __builtin_amdgcn_mfma_f32_16x16x32_bf16(ah[m], bh[n], acc[m][n], 0, 0, 0);
          acc[m][n] = __builtin_amdgcn_mfma_f32_16x16x32_bf16(ah[m], bl[n], acc[m][n], 0, 0, 0);
          acc[m][n] = __builtin_amdgcn_mfma_f32_16x16x32_bf16(al[m], bh[n], acc[m][n], 0, 0, 0);
        }
    }
  }
#pragma unroll
  for (int n = 0; n < 4; ++n) {
    const int o = wn * 64 + n * 16 + col;
    const float bv = bo[o];
#pragma unroll
    for (int m = 0; m < 2; ++m) {
#pragma unroll
      for (int r = 0; r < 4; ++r) {
        const int pix = wm * 32 + m * 16 + quad * 4 + r;
        out[(size_t)(n0 + pix) * DIM_ + o] = acc[m][n][r] + bv;
      }
    }
  }
}

extern "C" void kernel_launch(void* const* d_in, const int* in_sizes, int n_in,
                              void* d_out, int out_size, void* d_ws, size_t ws_size,
                              hipStream_t stream) {
  const float* x    = (const float*)d_in[0];
  const float* temp = (const float*)d_in[1];
  const float* Wx   = (const float*)d_in[2];
  const float* bx   = (const float*)d_in[3];
  const float* Wfx  = (const float*)d_in[4];
  const float* bfx  = (const float*)d_in[5];
  const float* Ws   = (const float*)d_in[6];
  const float* bs   = (const float*)d_in[7];
  const float* Wq   = (const float*)d_in[8];
  const float* Wk   = (const float*)d_in[9];
  const float* Wv   = (const float*)d_in[10];
  const float* Wo   = (const float*)d_in[11];
  const float* bo   = (const float*)d_in[12];
  float* out = (float*)d_out;

  char* p = (char*)d_ws;
  ushort* WTH = (ushort*)p; p += (size_t)WT_PLANE * 2;
  ushort* WTL = (ushort*)p; p += (size_t)WT_PLANE * 2;
  ushort* XPTH = (ushort*)p; p += (size_t)XPT_PLANE * 2;
  ushort* XPTL = (ushort*)p; p += (size_t)XPT_PLANE * 2;
  float* LG  = (float*)p; p += (size_t)N_ * INNER_ * 4;   // logits -> packed w
  float* FXO = (float*)p; p += (size_t)N_ * INNER_ * 4;   // fx_mid
  float* TOK = (float*)p; p += (size_t)B_ * HEADS_ * G_ * DH_ * 4;
  float* NRM = (float*)p; p += (size_t)B_ * HEADS_ * G_ * 4;
  float* MQK = (float*)p; p += (size_t)DH_ * DH_ * 4;
  float* BC  = (float*)p; p += (size_t)INNER_ * 4;
  ushort* MHT = (ushort*)p; p += (size_t)INNER_ * DIM_ * 2;
  ushort* MLT = (ushort*)p; p += (size_t)INNER_ * DIM_ * 2;
  float* TP  = (float*)p; p += (size_t)512 * 4096 * 4;    // token partials
  float* NP  = (float*)p; p += (size_t)512 * 64 * 4;      // norm partials

  wfx_kernel<<<2304, 256, 0, stream>>>(Wfx, WTH, WTL);
  wcomp_kernel<<<dim3(9, 8), 256, 0, stream>>>(Wx, Ws, bx, bs, temp, WTH, WTL, BC);
  mqk_kernel<<<16, 256, 0, stream>>>(Wq, Wk, MQK);

  for (int b = 0; b < B_; ++b) {
    const float* xb = x + (size_t)b * N_ * DIM_;
    float* outb = out + (size_t)b * N_ * DIM_;
    float* tokb = TOK + (size_t)b * HEADS_ * G_ * DH_;
    float* nrmb = NRM + (size_t)b * HEADS_ * G_;

    pad_tile_kernel<<<8450, 256, 0, stream>>>(xb, XPTH, XPTL);
    conv_mfma_kernel<<<dim3(8, 128), 256, 0, stream>>>(XPTH, XPTL, WTH, WTL, BC, bfx, LG, FXO);
    slice_kernel<<<512, 256, 0, stream>>>(LG, FXO, TP, NP);
    reduce_kernel<<<129, 256, 0, stream>>>(TP, NP, tokb, nrmb);
    head_kernel<<<8, 256, 0, stream>>>(tokb, nrmb, MQK, Wv, Wo, MHT, MLT);
    fused_out_kernel<<<256, 256, 0, stream>>>((const unsigned int*)LG, MHT, MLT, bo, outb);
  }
}